// Round 1
// baseline (1281.667 us; speedup 1.0000x reference)
//
#include <hip/hip_runtime.h>
#include <math.h>

// Problem constants (derived at runtime from in_sizes where it matters)
#define HEADS 4
#define HID 32
#define FEAT 128   // HEADS*HID == IN == hidden width everywhere
#define SLOPE 0.2f

// ---------------------------------------------------------------------------
// CSR build: histogram of dst, exclusive scan (+1 self loop per node), scatter
// ---------------------------------------------------------------------------

__global__ void hist_kernel(const int* __restrict__ edge_index, int* __restrict__ deg, int E) {
    int e = blockIdx.x * 256 + threadIdx.x;
    if (e < E) atomicAdd(&deg[edge_index[E + e]], 1);
}

__global__ __launch_bounds__(1024) void scan_kernel(const int* __restrict__ deg,
                                                    int* __restrict__ rowptr,
                                                    int* __restrict__ cursor, int Nn) {
    __shared__ int sums[1024];
    int t = threadIdx.x;
    int CH = (Nn + 1023) / 1024;
    int b = t * CH;
    int s = 0;
    for (int i = 0; i < CH; i++) {
        int idx = b + i;
        if (idx < Nn) s += deg[idx] + 1;   // +1 = self loop
    }
    sums[t] = s;
    __syncthreads();
    for (int off = 1; off < 1024; off <<= 1) {
        int v = (t >= off) ? sums[t - off] : 0;
        __syncthreads();
        sums[t] += v;
        __syncthreads();
    }
    int run = (t == 0) ? 0 : sums[t - 1];
    for (int i = 0; i < CH; i++) {
        int idx = b + i;
        if (idx < Nn) {
            rowptr[idx] = run;
            cursor[idx] = run;
            run += deg[idx] + 1;
        }
    }
    if (t == 1023) rowptr[Nn] = run;
}

__global__ void scatter_kernel(const int* __restrict__ edge_index, int* __restrict__ cursor,
                               int* __restrict__ ssorted, int E, int Nn) {
    int e = blockIdx.x * 256 + threadIdx.x;
    if (e < E) {
        int d = edge_index[E + e];
        int srcv = edge_index[e];
        int pos = atomicAdd(&cursor[d], 1);
        ssorted[pos] = srcv;
    } else if (e < E + Nn) {
        int i = e - E;
        int pos = atomicAdd(&cursor[i], 1);
        ssorted[pos] = i;   // self loop
    }
}

// ---------------------------------------------------------------------------
// GEMM: out[N][128] = A[N][128] @ W[128][128], fp32 vector ALU.
// Block 256 threads computes 64 rows x 128 cols; thread = 8 rows x 4 cols.
// ---------------------------------------------------------------------------
#define BM 64
#define BK 32

__global__ __launch_bounds__(256) void gemm128(const float* __restrict__ A,
                                               const float* __restrict__ W,
                                               float* __restrict__ out, int nrows) {
    __shared__ float xs[BK][68];    // [k][row], stride 68 dwords keeps 16B alignment, breaks conflicts
    __shared__ float wsm[BK][128];  // [k][col]
    int tid = threadIdx.x;
    int cg = tid & 31;   // 4-col group
    int rg = tid >> 5;   // 8-row group
    int r0 = blockIdx.x * BM;
    float acc[8][4] = {};
    for (int k0 = 0; k0 < 128; k0 += BK) {
        // stage A tile (64 rows x 32 k) transposed into xs[k][row]
#pragma unroll
        for (int i = 0; i < 2; i++) {
            int fl = tid + i * 256;
            int row = fl >> 3, k4 = fl & 7;
            int gr = r0 + row;
            if (gr >= nrows) gr = nrows - 1;   // clamp; values unused via store guard
            const float4 v = *(const float4*)(A + (size_t)gr * FEAT + k0 + k4 * 4);
            xs[k4 * 4 + 0][row] = v.x;
            xs[k4 * 4 + 1][row] = v.y;
            xs[k4 * 4 + 2][row] = v.z;
            xs[k4 * 4 + 3][row] = v.w;
        }
        // stage W tile (32 k x 128 cols)
#pragma unroll
        for (int i = 0; i < 4; i++) {
            int fl = tid + i * 256;
            int k = fl >> 5, c4 = fl & 31;
            *(float4*)(&wsm[k][c4 * 4]) = *(const float4*)(W + (size_t)(k0 + k) * FEAT + c4 * 4);
        }
        __syncthreads();
#pragma unroll
        for (int k = 0; k < BK; k++) {
            float4 b = *(const float4*)(&wsm[k][cg * 4]);
            float4 a0 = *(const float4*)(&xs[k][rg * 8]);
            float4 a1 = *(const float4*)(&xs[k][rg * 8 + 4]);
            float a[8] = {a0.x, a0.y, a0.z, a0.w, a1.x, a1.y, a1.z, a1.w};
#pragma unroll
            for (int j = 0; j < 8; j++) {
                acc[j][0] += a[j] * b.x;
                acc[j][1] += a[j] * b.y;
                acc[j][2] += a[j] * b.z;
                acc[j][3] += a[j] * b.w;
            }
        }
        __syncthreads();
    }
#pragma unroll
    for (int j = 0; j < 8; j++) {
        int row = r0 + rg * 8 + j;
        if (row < nrows)
            *(float4*)(out + (size_t)row * FEAT + cg * 4) =
                make_float4(acc[j][0], acc[j][1], acc[j][2], acc[j][3]);
    }
}

// ---------------------------------------------------------------------------
// Per-node attention-score halves: s_src[n][h] = dot(xw[n,h,:], a_src[h,:])
// One 128-thread block per node.
// ---------------------------------------------------------------------------
__global__ __launch_bounds__(128) void scores_kernel(const float* __restrict__ xw,
                                                     const float* __restrict__ a_s,
                                                     const float* __restrict__ a_d,
                                                     float* __restrict__ ssrc,
                                                     float* __restrict__ sdst) {
    int n = blockIdx.x;
    int t = threadIdx.x;
    float v = xw[(size_t)n * FEAT + t];
    int h = t >> 5;
    float ps = v * a_s[t];
    float pd = v * a_d[t];
#pragma unroll
    for (int m = 16; m >= 1; m >>= 1) {
        ps += __shfl_xor(ps, m);
        pd += __shfl_xor(pd, m);
    }
    if ((t & 31) == 0) {
        ssrc[n * HEADS + h] = ps;
        sdst[n * HEADS + h] = pd;
    }
}

// ---------------------------------------------------------------------------
// Edge softmax + aggregate, one 128-thread block per dst node.
// Thread t owns output channel t (head h = t/32). Head reductions stay within
// one wave's 32-lane half (block = 2 waves, heads 0,1 in wave0; 2,3 in wave1).
// ---------------------------------------------------------------------------
__global__ __launch_bounds__(128) void edge_agg(const float* __restrict__ xw,
                                                const float* __restrict__ ssrc,
                                                const float* __restrict__ sdst,
                                                const int* __restrict__ rowptr,
                                                const int* __restrict__ ssorted,
                                                const float* __restrict__ bias,
                                                float* __restrict__ out,
                                                int final_layer) {
    int n = blockIdx.x;
    int t = threadIdx.x;
    int h = t >> 5;
    int lane = t & 31;
    int beg = rowptr[n], end = rowptr[n + 1];
    float sd = sdst[n * HEADS + h];

    // pass 1: segment max per head
    float m = -1e30f;
    for (int e = beg + lane; e < end; e += 32) {
        int s = ssorted[e];
        float sc = ssrc[s * HEADS + h] + sd;
        sc = sc > 0.f ? sc : SLOPE * sc;
        m = fmaxf(m, sc);
    }
#pragma unroll
    for (int k = 16; k >= 1; k >>= 1) m = fmaxf(m, __shfl_xor(m, k));

    // pass 2: sum of exp
    float den = 0.f;
    for (int e = beg + lane; e < end; e += 32) {
        int s = ssorted[e];
        float sc = ssrc[s * HEADS + h] + sd;
        sc = sc > 0.f ? sc : SLOPE * sc;
        den += __expf(sc - m);
    }
#pragma unroll
    for (int k = 16; k >= 1; k >>= 1) den += __shfl_xor(den, k);
    float inv = 1.f / den;   // den >= 1 (max edge contributes exp(0)); ref clamps at 1e-16

    // pass 3: weighted gather-sum; weight recomputed (broadcast read + cheap exp)
    float acc = 0.f;
    for (int e = beg; e < end; e++) {
        int s = ssorted[e];
        float sc = ssrc[s * HEADS + h] + sd;
        sc = sc > 0.f ? sc : SLOPE * sc;
        float w = __expf(sc - m) * inv;
        acc += w * xw[(size_t)s * FEAT + t];
    }

    if (!final_layer) {
        float v = acc + bias[t];
        out[(size_t)n * FEAT + t] = v > 0.f ? v : expm1f(v);   // ELU
    } else {
        __shared__ float red[FEAT];
        red[t] = acc;
        __syncthreads();
        if (t < HID) {
            float v = (red[t] + red[t + 32] + red[t + 64] + red[t + 96]) * 0.25f + bias[t];
            out[(size_t)n * HID + t] = v;
        }
    }
}

// ---------------------------------------------------------------------------
// Launch
// ---------------------------------------------------------------------------
extern "C" void kernel_launch(void* const* d_in, const int* in_sizes, int n_in,
                              void* d_out, int out_size, void* d_ws, size_t ws_size,
                              hipStream_t stream) {
    const float* x   = (const float*)d_in[0];
    const int* eidx  = (const int*)d_in[1];
    const float* W1  = (const float*)d_in[2];
    const float* as1 = (const float*)d_in[3];
    const float* ad1 = (const float*)d_in[4];
    const float* b1  = (const float*)d_in[5];
    const float* W2  = (const float*)d_in[6];
    const float* as2 = (const float*)d_in[7];
    const float* ad2 = (const float*)d_in[8];
    const float* b2  = (const float*)d_in[9];
    const float* W3  = (const float*)d_in[10];
    const float* as3 = (const float*)d_in[11];
    const float* ad3 = (const float*)d_in[12];
    const float* b3  = (const float*)d_in[13];

    const int Nn = in_sizes[0] / FEAT;   // 100000
    const int E  = in_sizes[1] / 2;      // 1200000
    const int EP = E + Nn;

    // workspace carve-up
    char* w = (char*)d_ws;
    size_t off = 0;
    auto alloc = [&](size_t bytes) {
        void* p = w + off;
        off += (bytes + 255) & ~(size_t)255;
        return p;
    };
    float* bufA   = (float*)alloc((size_t)Nn * FEAT * 4);  // xw (post-GEMM)
    float* bufB   = (float*)alloc((size_t)Nn * FEAT * 4);  // layer output
    float* ssrc   = (float*)alloc((size_t)Nn * HEADS * 4);
    float* sdst   = (float*)alloc((size_t)Nn * HEADS * 4);
    int*   rowptr = (int*)alloc((size_t)(Nn + 1) * 4);
    int*   cursor = (int*)alloc((size_t)Nn * 4);
    int*   deg    = (int*)alloc((size_t)Nn * 4);
    int*   ssort  = (int*)alloc((size_t)EP * 4);
    (void)ws_size;

    // ---- CSR build (once per call; shared by all 3 layers)
    hipMemsetAsync(deg, 0, (size_t)Nn * 4, stream);
    hist_kernel<<<(E + 255) / 256, 256, 0, stream>>>(eidx, deg, E);
    scan_kernel<<<1, 1024, 0, stream>>>(deg, rowptr, cursor, Nn);
    scatter_kernel<<<(EP + 255) / 256, 256, 0, stream>>>(eidx, cursor, ssort, E, Nn);

    int gemm_grid = (Nn + BM - 1) / BM;

    // ---- layer 1
    gemm128<<<gemm_grid, 256, 0, stream>>>(x, W1, bufA, Nn);
    scores_kernel<<<Nn, 128, 0, stream>>>(bufA, as1, ad1, ssrc, sdst);
    edge_agg<<<Nn, 128, 0, stream>>>(bufA, ssrc, sdst, rowptr, ssort, b1, bufB, 0);

    // ---- layer 2
    gemm128<<<gemm_grid, 256, 0, stream>>>(bufB, W2, bufA, Nn);
    scores_kernel<<<Nn, 128, 0, stream>>>(bufA, as2, ad2, ssrc, sdst);
    edge_agg<<<Nn, 128, 0, stream>>>(bufA, ssrc, sdst, rowptr, ssort, b2, bufB, 0);

    // ---- layer 3 (mean over heads, no ELU)
    gemm128<<<gemm_grid, 256, 0, stream>>>(bufB, W3, bufA, Nn);
    scores_kernel<<<Nn, 128, 0, stream>>>(bufA, as3, ad3, ssrc, sdst);
    edge_agg<<<Nn, 128, 0, stream>>>(bufA, ssrc, sdst, rowptr, ssort, b3, (float*)d_out, 1);
}

// Round 2
// 1048.602 us; speedup vs baseline: 1.2223x; 1.2223x over previous
//
#include <hip/hip_runtime.h>
#include <math.h>

#define HEADS 4
#define HID 32
#define FEAT 128   // HEADS*HID == IN == hidden width everywhere
#define SLOPE 0.2f

// ---------------------------------------------------------------------------
// CSR build: histogram of dst, device-wide exclusive scan (+1 self loop per
// node), scatter. Scan is 3-phase multi-block (single-block scan was 256 us).
// ---------------------------------------------------------------------------

__global__ void hist_kernel(const int* __restrict__ edge_index, int* __restrict__ deg, int E) {
    int e = blockIdx.x * 256 + threadIdx.x;
    if (e < E) atomicAdd(&deg[edge_index[E + e]], 1);
}

#define SCAN_BLK 1024
#define SCAN_CHUNK 4
#define SCAN_TILE (SCAN_BLK * SCAN_CHUNK)   // 4096 elements per block

__global__ __launch_bounds__(SCAN_BLK) void scan_partial(const int* __restrict__ deg,
                                                         int* __restrict__ bsum, int Nn) {
    __shared__ int red[SCAN_BLK];
    int t = threadIdx.x;
    int base = blockIdx.x * SCAN_TILE + t * SCAN_CHUNK;
    int s = 0;
#pragma unroll
    for (int i = 0; i < SCAN_CHUNK; i++) {
        int idx = base + i;
        if (idx < Nn) s += deg[idx] + 1;   // +1 = self loop
    }
    red[t] = s;
    __syncthreads();
    for (int off = SCAN_BLK / 2; off >= 1; off >>= 1) {
        if (t < off) red[t] += red[t + off];
        __syncthreads();
    }
    if (t == 0) bsum[blockIdx.x] = red[0];
}

__global__ __launch_bounds__(64) void scan_bsum(int* __restrict__ bsum, int nb) {
    int t = threadIdx.x;   // one wave; nb <= 64
    int v = (t < nb) ? bsum[t] : 0;
    int orig = v;
#pragma unroll
    for (int off = 1; off < 64; off <<= 1) {
        int u = __shfl_up(v, off);
        if (t >= off) v += u;
    }
    if (t < nb) bsum[t] = v - orig;   // exclusive
}

__global__ __launch_bounds__(SCAN_BLK) void scan_final(const int* __restrict__ deg,
                                                       const int* __restrict__ bsum,
                                                       int* __restrict__ rowptr,
                                                       int* __restrict__ cursor, int Nn) {
    __shared__ int sums[SCAN_BLK];
    int t = threadIdx.x;
    int base = blockIdx.x * SCAN_TILE + t * SCAN_CHUNK;
    int loc[SCAN_CHUNK];
    int s = 0;
#pragma unroll
    for (int i = 0; i < SCAN_CHUNK; i++) {
        int idx = base + i;
        int d = (idx < Nn) ? deg[idx] + 1 : 0;
        loc[i] = s;
        s += d;
    }
    sums[t] = s;
    __syncthreads();
    for (int off = 1; off < SCAN_BLK; off <<= 1) {
        int v = (t >= off) ? sums[t - off] : 0;
        __syncthreads();
        sums[t] += v;
        __syncthreads();
    }
    int texcl = (t == 0) ? 0 : sums[t - 1];
    int offn = bsum[blockIdx.x] + texcl;
#pragma unroll
    for (int i = 0; i < SCAN_CHUNK; i++) {
        int idx = base + i;
        if (idx < Nn) {
            int v = offn + loc[i];
            rowptr[idx] = v;
            cursor[idx] = v;
        }
    }
    if (blockIdx.x == gridDim.x - 1 && t == SCAN_BLK - 1)
        rowptr[Nn] = offn + s;   // grand total = E + Nn
}

__global__ void scatter_kernel(const int* __restrict__ edge_index, int* __restrict__ cursor,
                               int* __restrict__ ssorted, int E, int Nn) {
    int e = blockIdx.x * 256 + threadIdx.x;
    if (e < E) {
        int d = edge_index[E + e];
        int srcv = edge_index[e];
        int pos = atomicAdd(&cursor[d], 1);
        ssorted[pos] = srcv;
    } else if (e < E + Nn) {
        int i = e - E;
        int pos = atomicAdd(&cursor[i], 1);
        ssorted[pos] = i;   // self loop
    }
}

// ---------------------------------------------------------------------------
// GEMM: out[N][128] = A[N][128] @ W[128][128], fp32 vector ALU.
// Block 256 threads computes 64 rows x 128 cols; thread = 8 rows x 4 cols.
// ---------------------------------------------------------------------------
#define BM 64
#define BK 32

__global__ __launch_bounds__(256) void gemm128(const float* __restrict__ A,
                                               const float* __restrict__ W,
                                               float* __restrict__ out, int nrows) {
    __shared__ float xs[BK][68];    // [k][row], stride 68 keeps 16B align, breaks conflicts
    __shared__ float wsm[BK][128];  // [k][col]
    int tid = threadIdx.x;
    int cg = tid & 31;   // 4-col group
    int rg = tid >> 5;   // 8-row group
    int r0 = blockIdx.x * BM;
    float acc[8][4] = {};
    for (int k0 = 0; k0 < 128; k0 += BK) {
#pragma unroll
        for (int i = 0; i < 2; i++) {
            int fl = tid + i * 256;
            int row = fl >> 3, k4 = fl & 7;
            int gr = r0 + row;
            if (gr >= nrows) gr = nrows - 1;   // clamp; values unused via store guard
            const float4 v = *(const float4*)(A + (size_t)gr * FEAT + k0 + k4 * 4);
            xs[k4 * 4 + 0][row] = v.x;
            xs[k4 * 4 + 1][row] = v.y;
            xs[k4 * 4 + 2][row] = v.z;
            xs[k4 * 4 + 3][row] = v.w;
        }
#pragma unroll
        for (int i = 0; i < 4; i++) {
            int fl = tid + i * 256;
            int k = fl >> 5, c4 = fl & 31;
            *(float4*)(&wsm[k][c4 * 4]) = *(const float4*)(W + (size_t)(k0 + k) * FEAT + c4 * 4);
        }
        __syncthreads();
#pragma unroll
        for (int k = 0; k < BK; k++) {
            float4 b = *(const float4*)(&wsm[k][cg * 4]);
            float4 a0 = *(const float4*)(&xs[k][rg * 8]);
            float4 a1 = *(const float4*)(&xs[k][rg * 8 + 4]);
            float a[8] = {a0.x, a0.y, a0.z, a0.w, a1.x, a1.y, a1.z, a1.w};
#pragma unroll
            for (int j = 0; j < 8; j++) {
                acc[j][0] += a[j] * b.x;
                acc[j][1] += a[j] * b.y;
                acc[j][2] += a[j] * b.z;
                acc[j][3] += a[j] * b.w;
            }
        }
        __syncthreads();
    }
#pragma unroll
    for (int j = 0; j < 8; j++) {
        int row = r0 + rg * 8 + j;
        if (row < nrows)
            *(float4*)(out + (size_t)row * FEAT + cg * 4) =
                make_float4(acc[j][0], acc[j][1], acc[j][2], acc[j][3]);
    }
}

// ---------------------------------------------------------------------------
// Per-node attention-score halves: s_src[n][h] = dot(xw[n,h,:], a_src[h,:])
// ---------------------------------------------------------------------------
__global__ __launch_bounds__(128) void scores_kernel(const float* __restrict__ xw,
                                                     const float* __restrict__ a_s,
                                                     const float* __restrict__ a_d,
                                                     float* __restrict__ ssrc,
                                                     float* __restrict__ sdst) {
    int n = blockIdx.x;
    int t = threadIdx.x;
    float v = xw[(size_t)n * FEAT + t];
    int h = t >> 5;
    float ps = v * a_s[t];
    float pd = v * a_d[t];
#pragma unroll
    for (int m = 16; m >= 1; m >>= 1) {
        ps += __shfl_xor(ps, m);
        pd += __shfl_xor(pd, m);
    }
    if ((t & 31) == 0) {
        ssrc[n * HEADS + h] = ps;
        sdst[n * HEADS + h] = pd;
    }
}

// ---------------------------------------------------------------------------
// Edge softmax + aggregate, one 128-thread block per dst node.
// ---------------------------------------------------------------------------
__global__ __launch_bounds__(128) void edge_agg(const float* __restrict__ xw,
                                                const float* __restrict__ ssrc,
                                                const float* __restrict__ sdst,
                                                const int* __restrict__ rowptr,
                                                const int* __restrict__ ssorted,
                                                const float* __restrict__ bias,
                                                float* __restrict__ out,
                                                int final_layer) {
    int n = blockIdx.x;
    int t = threadIdx.x;
    int h = t >> 5;
    int lane = t & 31;
    int beg = rowptr[n], end = rowptr[n + 1];
    float sd = sdst[n * HEADS + h];

    // pass 1: segment max per head
    float m = -1e30f;
    for (int e = beg + lane; e < end; e += 32) {
        int s = ssorted[e];
        float sc = ssrc[s * HEADS + h] + sd;
        sc = sc > 0.f ? sc : SLOPE * sc;
        m = fmaxf(m, sc);
    }
#pragma unroll
    for (int k = 16; k >= 1; k >>= 1) m = fmaxf(m, __shfl_xor(m, k));

    // pass 2: sum of exp
    float den = 0.f;
    for (int e = beg + lane; e < end; e += 32) {
        int s = ssorted[e];
        float sc = ssrc[s * HEADS + h] + sd;
        sc = sc > 0.f ? sc : SLOPE * sc;
        den += __expf(sc - m);
    }
#pragma unroll
    for (int k = 16; k >= 1; k >>= 1) den += __shfl_xor(den, k);
    float inv = 1.f / den;

    // pass 3: weighted gather-sum
    float acc = 0.f;
    for (int e = beg; e < end; e++) {
        int s = ssorted[e];
        float sc = ssrc[s * HEADS + h] + sd;
        sc = sc > 0.f ? sc : SLOPE * sc;
        float w = __expf(sc - m) * inv;
        acc += w * xw[(size_t)s * FEAT + t];
    }

    if (!final_layer) {
        float v = acc + bias[t];
        out[(size_t)n * FEAT + t] = v > 0.f ? v : expm1f(v);   // ELU
    } else {
        __shared__ float red[FEAT];
        red[t] = acc;
        __syncthreads();
        if (t < HID) {
            float v = (red[t] + red[t + 32] + red[t + 64] + red[t + 96]) * 0.25f + bias[t];
            out[(size_t)n * HID + t] = v;
        }
    }
}

// ---------------------------------------------------------------------------
// Launch
// ---------------------------------------------------------------------------
extern "C" void kernel_launch(void* const* d_in, const int* in_sizes, int n_in,
                              void* d_out, int out_size, void* d_ws, size_t ws_size,
                              hipStream_t stream) {
    const float* x   = (const float*)d_in[0];
    const int* eidx  = (const int*)d_in[1];
    const float* W1  = (const float*)d_in[2];
    const float* as1 = (const float*)d_in[3];
    const float* ad1 = (const float*)d_in[4];
    const float* b1  = (const float*)d_in[5];
    const float* W2  = (const float*)d_in[6];
    const float* as2 = (const float*)d_in[7];
    const float* ad2 = (const float*)d_in[8];
    const float* b2  = (const float*)d_in[9];
    const float* W3  = (const float*)d_in[10];
    const float* as3 = (const float*)d_in[11];
    const float* ad3 = (const float*)d_in[12];
    const float* b3  = (const float*)d_in[13];

    const int Nn = in_sizes[0] / FEAT;   // 100000
    const int E  = in_sizes[1] / 2;      // 1200000
    const int EP = E + Nn;

    char* w = (char*)d_ws;
    size_t off = 0;
    auto alloc = [&](size_t bytes) {
        void* p = w + off;
        off += (bytes + 255) & ~(size_t)255;
        return p;
    };
    float* bufA   = (float*)alloc((size_t)Nn * FEAT * 4);
    float* bufB   = (float*)alloc((size_t)Nn * FEAT * 4);
    float* ssrc   = (float*)alloc((size_t)Nn * HEADS * 4);
    float* sdst   = (float*)alloc((size_t)Nn * HEADS * 4);
    int*   rowptr = (int*)alloc((size_t)(Nn + 1) * 4);
    int*   cursor = (int*)alloc((size_t)Nn * 4);
    int*   deg    = (int*)alloc((size_t)Nn * 4);
    int*   ssort  = (int*)alloc((size_t)EP * 4);
    int*   bsum   = (int*)alloc(64 * 4);
    (void)ws_size;

    // ---- CSR build (once per call; shared by all 3 layers)
    hipMemsetAsync(deg, 0, (size_t)Nn * 4, stream);
    hist_kernel<<<(E + 255) / 256, 256, 0, stream>>>(eidx, deg, E);
    int nscan = (Nn + SCAN_TILE - 1) / SCAN_TILE;   // 25 for N=100000 (must be <= 64)
    scan_partial<<<nscan, SCAN_BLK, 0, stream>>>(deg, bsum, Nn);
    scan_bsum<<<1, 64, 0, stream>>>(bsum, nscan);
    scan_final<<<nscan, SCAN_BLK, 0, stream>>>(deg, bsum, rowptr, cursor, Nn);
    scatter_kernel<<<(EP + 255) / 256, 256, 0, stream>>>(eidx, cursor, ssort, E, Nn);

    int gemm_grid = (Nn + BM - 1) / BM;

    // ---- layer 1
    gemm128<<<gemm_grid, 256, 0, stream>>>(x, W1, bufA, Nn);
    scores_kernel<<<Nn, 128, 0, stream>>>(bufA, as1, ad1, ssrc, sdst);
    edge_agg<<<Nn, 128, 0, stream>>>(bufA, ssrc, sdst, rowptr, ssort, b1, bufB, 0);

    // ---- layer 2
    gemm128<<<gemm_grid, 256, 0, stream>>>(bufB, W2, bufA, Nn);
    scores_kernel<<<Nn, 128, 0, stream>>>(bufA, as2, ad2, ssrc, sdst);
    edge_agg<<<Nn, 128, 0, stream>>>(bufA, ssrc, sdst, rowptr, ssort, b2, bufB, 0);

    // ---- layer 3 (mean over heads, no ELU)
    gemm128<<<gemm_grid, 256, 0, stream>>>(bufB, W3, bufA, Nn);
    scores_kernel<<<Nn, 128, 0, stream>>>(bufA, as3, ad3, ssrc, sdst);
    edge_agg<<<Nn, 128, 0, stream>>>(bufA, ssrc, sdst, rowptr, ssort, b3, (float*)d_out, 1);
}

// Round 3
// 873.754 us; speedup vs baseline: 1.4669x; 1.2001x over previous
//
#include <hip/hip_runtime.h>
#include <math.h>

#define HEADS 4
#define HID 32
#define FEAT 128   // HEADS*HID == IN == hidden width everywhere
#define SLOPE 0.2f

// ---------------------------------------------------------------------------
// CSR build: histogram of dst, device-wide exclusive scan (+1 self loop per
// node), scatter.
// ---------------------------------------------------------------------------

__global__ void hist_kernel(const int* __restrict__ edge_index, int* __restrict__ deg, int E) {
    int e = blockIdx.x * 256 + threadIdx.x;
    if (e < E) atomicAdd(&deg[edge_index[E + e]], 1);
}

#define SCAN_BLK 1024
#define SCAN_CHUNK 4
#define SCAN_TILE (SCAN_BLK * SCAN_CHUNK)   // 4096 elements per block

__global__ __launch_bounds__(SCAN_BLK) void scan_partial(const int* __restrict__ deg,
                                                         int* __restrict__ bsum, int Nn) {
    __shared__ int red[SCAN_BLK];
    int t = threadIdx.x;
    int base = blockIdx.x * SCAN_TILE + t * SCAN_CHUNK;
    int s = 0;
#pragma unroll
    for (int i = 0; i < SCAN_CHUNK; i++) {
        int idx = base + i;
        if (idx < Nn) s += deg[idx] + 1;   // +1 = self loop
    }
    red[t] = s;
    __syncthreads();
    for (int off = SCAN_BLK / 2; off >= 1; off >>= 1) {
        if (t < off) red[t] += red[t + off];
        __syncthreads();
    }
    if (t == 0) bsum[blockIdx.x] = red[0];
}

__global__ __launch_bounds__(64) void scan_bsum(int* __restrict__ bsum, int nb) {
    int t = threadIdx.x;   // one wave; nb <= 64
    int v = (t < nb) ? bsum[t] : 0;
    int orig = v;
#pragma unroll
    for (int off = 1; off < 64; off <<= 1) {
        int u = __shfl_up(v, off);
        if (t >= off) v += u;
    }
    if (t < nb) bsum[t] = v - orig;   // exclusive
}

__global__ __launch_bounds__(SCAN_BLK) void scan_final(const int* __restrict__ deg,
                                                       const int* __restrict__ bsum,
                                                       int* __restrict__ rowptr,
                                                       int* __restrict__ cursor, int Nn) {
    __shared__ int sums[SCAN_BLK];
    int t = threadIdx.x;
    int base = blockIdx.x * SCAN_TILE + t * SCAN_CHUNK;
    int loc[SCAN_CHUNK];
    int s = 0;
#pragma unroll
    for (int i = 0; i < SCAN_CHUNK; i++) {
        int idx = base + i;
        int d = (idx < Nn) ? deg[idx] + 1 : 0;
        loc[i] = s;
        s += d;
    }
    sums[t] = s;
    __syncthreads();
    for (int off = 1; off < SCAN_BLK; off <<= 1) {
        int v = (t >= off) ? sums[t - off] : 0;
        __syncthreads();
        sums[t] += v;
        __syncthreads();
    }
    int texcl = (t == 0) ? 0 : sums[t - 1];
    int offn = bsum[blockIdx.x] + texcl;
#pragma unroll
    for (int i = 0; i < SCAN_CHUNK; i++) {
        int idx = base + i;
        if (idx < Nn) {
            int v = offn + loc[i];
            rowptr[idx] = v;
            cursor[idx] = v;
        }
    }
    if (blockIdx.x == gridDim.x - 1 && t == SCAN_BLK - 1)
        rowptr[Nn] = offn + s;   // grand total = E + Nn
}

__global__ void scatter_kernel(const int* __restrict__ edge_index, int* __restrict__ cursor,
                               int* __restrict__ ssorted, int E, int Nn) {
    int e = blockIdx.x * 256 + threadIdx.x;
    if (e < E) {
        int d = edge_index[E + e];
        int srcv = edge_index[e];
        int pos = atomicAdd(&cursor[d], 1);
        ssorted[pos] = srcv;
    } else if (e < E + Nn) {
        int i = e - E;
        int pos = atomicAdd(&cursor[i], 1);
        ssorted[pos] = i;   // self loop
    }
}

// ---------------------------------------------------------------------------
// GEMM: out[N][128] = A[N][128] @ W[128][128], fp32 vector ALU.
// ---------------------------------------------------------------------------
#define BM 64
#define BK 32

__global__ __launch_bounds__(256) void gemm128(const float* __restrict__ A,
                                               const float* __restrict__ W,
                                               float* __restrict__ out, int nrows) {
    __shared__ float xs[BK][68];
    __shared__ float wsm[BK][128];
    int tid = threadIdx.x;
    int cg = tid & 31;
    int rg = tid >> 5;
    int r0 = blockIdx.x * BM;
    float acc[8][4] = {};
    for (int k0 = 0; k0 < 128; k0 += BK) {
#pragma unroll
        for (int i = 0; i < 2; i++) {
            int fl = tid + i * 256;
            int row = fl >> 3, k4 = fl & 7;
            int gr = r0 + row;
            if (gr >= nrows) gr = nrows - 1;
            const float4 v = *(const float4*)(A + (size_t)gr * FEAT + k0 + k4 * 4);
            xs[k4 * 4 + 0][row] = v.x;
            xs[k4 * 4 + 1][row] = v.y;
            xs[k4 * 4 + 2][row] = v.z;
            xs[k4 * 4 + 3][row] = v.w;
        }
#pragma unroll
        for (int i = 0; i < 4; i++) {
            int fl = tid + i * 256;
            int k = fl >> 5, c4 = fl & 31;
            *(float4*)(&wsm[k][c4 * 4]) = *(const float4*)(W + (size_t)(k0 + k) * FEAT + c4 * 4);
        }
        __syncthreads();
#pragma unroll
        for (int k = 0; k < BK; k++) {
            float4 b = *(const float4*)(&wsm[k][cg * 4]);
            float4 a0 = *(const float4*)(&xs[k][rg * 8]);
            float4 a1 = *(const float4*)(&xs[k][rg * 8 + 4]);
            float a[8] = {a0.x, a0.y, a0.z, a0.w, a1.x, a1.y, a1.z, a1.w};
#pragma unroll
            for (int j = 0; j < 8; j++) {
                acc[j][0] += a[j] * b.x;
                acc[j][1] += a[j] * b.y;
                acc[j][2] += a[j] * b.z;
                acc[j][3] += a[j] * b.w;
            }
        }
        __syncthreads();
    }
#pragma unroll
    for (int j = 0; j < 8; j++) {
        int row = r0 + rg * 8 + j;
        if (row < nrows)
            *(float4*)(out + (size_t)row * FEAT + cg * 4) =
                make_float4(acc[j][0], acc[j][1], acc[j][2], acc[j][3]);
    }
}

// ---------------------------------------------------------------------------
// Per-node attention-score halves
// ---------------------------------------------------------------------------
__global__ __launch_bounds__(128) void scores_kernel(const float* __restrict__ xw,
                                                     const float* __restrict__ a_s,
                                                     const float* __restrict__ a_d,
                                                     float* __restrict__ ssrc,
                                                     float* __restrict__ sdst) {
    int n = blockIdx.x;
    int t = threadIdx.x;
    float v = xw[(size_t)n * FEAT + t];
    int h = t >> 5;
    float ps = v * a_s[t];
    float pd = v * a_d[t];
#pragma unroll
    for (int m = 16; m >= 1; m >>= 1) {
        ps += __shfl_xor(ps, m);
        pd += __shfl_xor(pd, m);
    }
    if ((t & 31) == 0) {
        ssrc[n * HEADS + h] = ps;
        sdst[n * HEADS + h] = pd;
    }
}

// ---------------------------------------------------------------------------
// Edge softmax + aggregate, one 128-thread block per dst node.
// Passes 1&2: thread = (head h=t/32, lane=t%32), strided reduction for m, den.
// Pass 3:     thread = (edge-slot j=t/32, channel-quad q=t%32); weights for a
//             32-edge chunk are computed ONCE per (edge,head) into LDS, then
//             the gather runs 4 edges concurrently with float4 loads.
// ---------------------------------------------------------------------------
__global__ __launch_bounds__(128) void edge_agg(const float* __restrict__ xw,
                                                const float* __restrict__ ssrc,
                                                const float* __restrict__ sdst,
                                                const int* __restrict__ rowptr,
                                                const int* __restrict__ ssorted,
                                                const float* __restrict__ bias,
                                                float* __restrict__ out,
                                                int final_layer) {
    int n = blockIdx.x;
    int t = threadIdx.x;
    int beg = rowptr[n], end = rowptr[n + 1];

    __shared__ float mh[HEADS], invh[HEADS], sdh[HEADS];
    __shared__ float wbuf[32][HEADS];
    __shared__ int   sbuf[32];
    __shared__ float red[128][4];

    // ---- passes 1 & 2: per-head segment max and sum-exp
    {
        int h = t >> 5, lane = t & 31;
        float sd = sdst[n * HEADS + h];
        if (lane == 0) sdh[h] = sd;
        float m = -1e30f;
        for (int e = beg + lane; e < end; e += 32) {
            int s = ssorted[e];
            float sc = ssrc[s * HEADS + h] + sd;
            sc = sc > 0.f ? sc : SLOPE * sc;
            m = fmaxf(m, sc);
        }
#pragma unroll
        for (int k = 16; k >= 1; k >>= 1) m = fmaxf(m, __shfl_xor(m, k));
        float den = 0.f;
        for (int e = beg + lane; e < end; e += 32) {
            int s = ssorted[e];
            float sc = ssrc[s * HEADS + h] + sd;
            sc = sc > 0.f ? sc : SLOPE * sc;
            den += __expf(sc - m);
        }
#pragma unroll
        for (int k = 16; k >= 1; k >>= 1) den += __shfl_xor(den, k);
        if (lane == 0) { mh[h] = m; invh[h] = 1.f / den; }
    }
    __syncthreads();

    // ---- pass 3: chunked weight precompute + 4-edge-parallel float4 gather
    int j = t >> 5;        // edge slot 0..3
    int q = t & 31;        // channel quad (channels 4q..4q+3)
    int qh = q >> 3;       // head owning this quad
    float4 acc = make_float4(0.f, 0.f, 0.f, 0.f);

    for (int cb = beg; cb < end; cb += 32) {
        int c = end - cb; if (c > 32) c = 32;
        {   // weights: thread (l = t/4, hh = t%4)
            int l = t >> 2, hh = t & 3;
            if (l < c) {
                int s = ssorted[cb + l];
                if (hh == 0) sbuf[l] = s;
                float sc = ssrc[s * HEADS + hh] + sdh[hh];
                sc = sc > 0.f ? sc : SLOPE * sc;
                wbuf[l][hh] = __expf(sc - mh[hh]) * invh[hh];
            }
        }
        __syncthreads();
        for (int i = j; i < c; i += 4) {
            int s = sbuf[i];
            float w = wbuf[i][qh];
            float4 v = *(const float4*)(xw + (size_t)s * FEAT + q * 4);
            acc.x += w * v.x; acc.y += w * v.y; acc.z += w * v.z; acc.w += w * v.w;
        }
        __syncthreads();
    }

    // ---- reduce over the 4 edge slots
    *(float4*)red[t] = acc;
    __syncthreads();

    if (!final_layer) {
        if (t < 32) {
            float4 r;
            r.x = red[t][0] + red[t + 32][0] + red[t + 64][0] + red[t + 96][0];
            r.y = red[t][1] + red[t + 32][1] + red[t + 64][1] + red[t + 96][1];
            r.z = red[t][2] + red[t + 32][2] + red[t + 64][2] + red[t + 96][2];
            r.w = red[t][3] + red[t + 32][3] + red[t + 64][3] + red[t + 96][3];
            const float4 b4 = *(const float4*)(bias + t * 4);
            r.x += b4.x; r.y += b4.y; r.z += b4.z; r.w += b4.w;
            r.x = r.x > 0.f ? r.x : expm1f(r.x);
            r.y = r.y > 0.f ? r.y : expm1f(r.y);
            r.z = r.z > 0.f ? r.z : expm1f(r.z);
            r.w = r.w > 0.f ? r.w : expm1f(r.w);
            *(float4*)(out + (size_t)n * FEAT + t * 4) = r;
        }
    } else {
        // per-quad totals into red[0..31], then mean over heads
        if (t < 32) {
            float4 r;
            r.x = red[t][0] + red[t + 32][0] + red[t + 64][0] + red[t + 96][0];
            r.y = red[t][1] + red[t + 32][1] + red[t + 64][1] + red[t + 96][1];
            r.z = red[t][2] + red[t + 32][2] + red[t + 64][2] + red[t + 96][2];
            r.w = red[t][3] + red[t + 32][3] + red[t + 64][3] + red[t + 96][3];
            __syncthreads();           // all 128 threads? no — guard below
            *(float4*)red[t] = r;      // overwrite slots 0..31
        }
        // NOTE: the __syncthreads above is inside `if (t<32)` which would hang;
        // restructure: do it with full-block barriers.
        __syncthreads();
        if (t < 8) {
            // channels 4t..4t+3 of the head-mean; channel h*32+c lives at quad h*8+c/4
            float4 r;
            r.x = (red[t][0] + red[t + 8][0] + red[t + 16][0] + red[t + 24][0]) * 0.25f;
            r.y = (red[t][1] + red[t + 8][1] + red[t + 16][1] + red[t + 24][1]) * 0.25f;
            r.z = (red[t][2] + red[t + 8][2] + red[t + 16][2] + red[t + 24][2]) * 0.25f;
            r.w = (red[t][3] + red[t + 8][3] + red[t + 16][3] + red[t + 24][3]) * 0.25f;
            const float4 b4 = *(const float4*)(bias + t * 4);
            r.x += b4.x; r.y += b4.y; r.z += b4.z; r.w += b4.w;
            *(float4*)(out + (size_t)n * HID + t * 4) = r;
        }
    }
}

// ---------------------------------------------------------------------------
// Launch
// ---------------------------------------------------------------------------
extern "C" void kernel_launch(void* const* d_in, const int* in_sizes, int n_in,
                              void* d_out, int out_size, void* d_ws, size_t ws_size,
                              hipStream_t stream) {
    const float* x   = (const float*)d_in[0];
    const int* eidx  = (const int*)d_in[1];
    const float* W1  = (const float*)d_in[2];
    const float* as1 = (const float*)d_in[3];
    const float* ad1 = (const float*)d_in[4];
    const float* b1  = (const float*)d_in[5];
    const float* W2  = (const float*)d_in[6];
    const float* as2 = (const float*)d_in[7];
    const float* ad2 = (const float*)d_in[8];
    const float* b2  = (const float*)d_in[9];
    const float* W3  = (const float*)d_in[10];
    const float* as3 = (const float*)d_in[11];
    const float* ad3 = (const float*)d_in[12];
    const float* b3  = (const float*)d_in[13];

    const int Nn = in_sizes[0] / FEAT;   // 100000
    const int E  = in_sizes[1] / 2;      // 1200000
    const int EP = E + Nn;

    char* w = (char*)d_ws;
    size_t off = 0;
    auto alloc = [&](size_t bytes) {
        void* p = w + off;
        off += (bytes + 255) & ~(size_t)255;
        return p;
    };
    float* bufA   = (float*)alloc((size_t)Nn * FEAT * 4);
    float* bufB   = (float*)alloc((size_t)Nn * FEAT * 4);
    float* ssrc   = (float*)alloc((size_t)Nn * HEADS * 4);
    float* sdst   = (float*)alloc((size_t)Nn * HEADS * 4);
    int*   rowptr = (int*)alloc((size_t)(Nn + 1) * 4);
    int*   cursor = (int*)alloc((size_t)Nn * 4);
    int*   deg    = (int*)alloc((size_t)Nn * 4);
    int*   ssort  = (int*)alloc((size_t)EP * 4);
    int*   bsum   = (int*)alloc(64 * 4);
    (void)ws_size;

    // ---- CSR build
    hipMemsetAsync(deg, 0, (size_t)Nn * 4, stream);
    hist_kernel<<<(E + 255) / 256, 256, 0, stream>>>(eidx, deg, E);
    int nscan = (Nn + SCAN_TILE - 1) / SCAN_TILE;   // 25 (must be <= 64)
    scan_partial<<<nscan, SCAN_BLK, 0, stream>>>(deg, bsum, Nn);
    scan_bsum<<<1, 64, 0, stream>>>(bsum, nscan);
    scan_final<<<nscan, SCAN_BLK, 0, stream>>>(deg, bsum, rowptr, cursor, Nn);
    scatter_kernel<<<(EP + 255) / 256, 256, 0, stream>>>(eidx, cursor, ssort, E, Nn);

    int gemm_grid = (Nn + BM - 1) / BM;

    // ---- layer 1
    gemm128<<<gemm_grid, 256, 0, stream>>>(x, W1, bufA, Nn);
    scores_kernel<<<Nn, 128, 0, stream>>>(bufA, as1, ad1, ssrc, sdst);
    edge_agg<<<Nn, 128, 0, stream>>>(bufA, ssrc, sdst, rowptr, ssort, b1, bufB, 0);

    // ---- layer 2
    gemm128<<<gemm_grid, 256, 0, stream>>>(bufB, W2, bufA, Nn);
    scores_kernel<<<Nn, 128, 0, stream>>>(bufA, as2, ad2, ssrc, sdst);
    edge_agg<<<Nn, 128, 0, stream>>>(bufA, ssrc, sdst, rowptr, ssort, b2, bufB, 0);

    // ---- layer 3 (mean over heads, no ELU)
    gemm128<<<gemm_grid, 256, 0, stream>>>(bufB, W3, bufA, Nn);
    scores_kernel<<<Nn, 128, 0, stream>>>(bufA, as3, ad3, ssrc, sdst);
    edge_agg<<<Nn, 128, 0, stream>>>(bufA, ssrc, sdst, rowptr, ssort, b3, (float*)d_out, 1);
}

// Round 4
// 851.298 us; speedup vs baseline: 1.5055x; 1.0264x over previous
//
#include <hip/hip_runtime.h>
#include <math.h>

#define HEADS 4
#define HID 32
#define FEAT 128   // HEADS*HID == IN == hidden width everywhere
#define SLOPE 0.2f

// ---------------------------------------------------------------------------
// CSR build: histogram of dst, device-wide exclusive scan (+1 self loop per
// node), scatter (emits src AND dst per sorted slot).
// ---------------------------------------------------------------------------

__global__ void hist_kernel(const int* __restrict__ edge_index, int* __restrict__ deg, int E) {
    int e = blockIdx.x * 256 + threadIdx.x;
    if (e < E) atomicAdd(&deg[edge_index[E + e]], 1);
}

#define SCAN_BLK 1024
#define SCAN_CHUNK 4
#define SCAN_TILE (SCAN_BLK * SCAN_CHUNK)

__global__ __launch_bounds__(SCAN_BLK) void scan_partial(const int* __restrict__ deg,
                                                         int* __restrict__ bsum, int Nn) {
    __shared__ int red[SCAN_BLK];
    int t = threadIdx.x;
    int base = blockIdx.x * SCAN_TILE + t * SCAN_CHUNK;
    int s = 0;
#pragma unroll
    for (int i = 0; i < SCAN_CHUNK; i++) {
        int idx = base + i;
        if (idx < Nn) s += deg[idx] + 1;
    }
    red[t] = s;
    __syncthreads();
    for (int off = SCAN_BLK / 2; off >= 1; off >>= 1) {
        if (t < off) red[t] += red[t + off];
        __syncthreads();
    }
    if (t == 0) bsum[blockIdx.x] = red[0];
}

__global__ __launch_bounds__(64) void scan_bsum(int* __restrict__ bsum, int nb) {
    int t = threadIdx.x;   // one wave; nb <= 64
    int v = (t < nb) ? bsum[t] : 0;
    int orig = v;
#pragma unroll
    for (int off = 1; off < 64; off <<= 1) {
        int u = __shfl_up(v, off);
        if (t >= off) v += u;
    }
    if (t < nb) bsum[t] = v - orig;   // exclusive
}

__global__ __launch_bounds__(SCAN_BLK) void scan_final(const int* __restrict__ deg,
                                                       const int* __restrict__ bsum,
                                                       int* __restrict__ rowptr,
                                                       int* __restrict__ cursor, int Nn) {
    __shared__ int sums[SCAN_BLK];
    int t = threadIdx.x;
    int base = blockIdx.x * SCAN_TILE + t * SCAN_CHUNK;
    int loc[SCAN_CHUNK];
    int s = 0;
#pragma unroll
    for (int i = 0; i < SCAN_CHUNK; i++) {
        int idx = base + i;
        int d = (idx < Nn) ? deg[idx] + 1 : 0;
        loc[i] = s;
        s += d;
    }
    sums[t] = s;
    __syncthreads();
    for (int off = 1; off < SCAN_BLK; off <<= 1) {
        int v = (t >= off) ? sums[t - off] : 0;
        __syncthreads();
        sums[t] += v;
        __syncthreads();
    }
    int texcl = (t == 0) ? 0 : sums[t - 1];
    int offn = bsum[blockIdx.x] + texcl;
#pragma unroll
    for (int i = 0; i < SCAN_CHUNK; i++) {
        int idx = base + i;
        if (idx < Nn) {
            int v = offn + loc[i];
            rowptr[idx] = v;
            cursor[idx] = v;
        }
    }
    if (blockIdx.x == gridDim.x - 1 && t == SCAN_BLK - 1)
        rowptr[Nn] = offn + s;
}

__global__ void scatter_kernel(const int* __restrict__ edge_index, int* __restrict__ cursor,
                               int* __restrict__ ssorted, int* __restrict__ dsorted,
                               int E, int Nn) {
    int e = blockIdx.x * 256 + threadIdx.x;
    if (e < E) {
        int d = edge_index[E + e];
        int srcv = edge_index[e];
        int pos = atomicAdd(&cursor[d], 1);
        ssorted[pos] = srcv;
        dsorted[pos] = d;
    } else if (e < E + Nn) {
        int i = e - E;
        int pos = atomicAdd(&cursor[i], 1);
        ssorted[pos] = i;
        dsorted[pos] = i;
    }
}

// ---------------------------------------------------------------------------
// GEMM: out[N][128] = A[N][128] @ W[128][128], fp32 vector ALU.
// 128x128 block tile, 256 threads, 8x8 per-thread tile, BK=32.
// ---------------------------------------------------------------------------
#define GBM 128
#define GBK 32

__global__ __launch_bounds__(256) void gemm128(const float* __restrict__ A,
                                               const float* __restrict__ W,
                                               float* __restrict__ out, int nrows) {
    __shared__ float xs[GBK][GBM + 4];   // [k][row], pad keeps 16B align
    __shared__ float wsm[GBK][FEAT];     // [k][col]
    int tid = threadIdx.x;
    int cg = tid & 15;    // cols cg*8 .. cg*8+7
    int rg = tid >> 4;    // rows rg*8 .. rg*8+7
    int r0 = blockIdx.x * GBM;
    float acc[8][8] = {};
    for (int k0 = 0; k0 < FEAT; k0 += GBK) {
        // stage A: 128 rows x 32 k = 1024 float4; 4 per thread, transposed into xs
#pragma unroll
        for (int i = 0; i < 4; i++) {
            int f = tid + i * 256;
            int row = f >> 3, k4 = f & 7;
            int gr = r0 + row;
            if (gr >= nrows) gr = nrows - 1;   // clamp; store-guarded later
            const float4 v = *(const float4*)(A + (size_t)gr * FEAT + k0 + k4 * 4);
            xs[k4 * 4 + 0][row] = v.x;
            xs[k4 * 4 + 1][row] = v.y;
            xs[k4 * 4 + 2][row] = v.z;
            xs[k4 * 4 + 3][row] = v.w;
        }
        // stage W: 32 k x 128 cols = 1024 float4; 4 per thread
#pragma unroll
        for (int i = 0; i < 4; i++) {
            int f = tid + i * 256;
            int k = f >> 5, c4 = f & 31;
            *(float4*)(&wsm[k][c4 * 4]) = *(const float4*)(W + (size_t)(k0 + k) * FEAT + c4 * 4);
        }
        __syncthreads();
#pragma unroll
        for (int k = 0; k < GBK; k++) {
            float4 a0 = *(const float4*)(&xs[k][rg * 8]);
            float4 a1 = *(const float4*)(&xs[k][rg * 8 + 4]);
            float4 b0 = *(const float4*)(&wsm[k][cg * 8]);
            float4 b1 = *(const float4*)(&wsm[k][cg * 8 + 4]);
            float a[8] = {a0.x, a0.y, a0.z, a0.w, a1.x, a1.y, a1.z, a1.w};
            float b[8] = {b0.x, b0.y, b0.z, b0.w, b1.x, b1.y, b1.z, b1.w};
#pragma unroll
            for (int j = 0; j < 8; j++)
#pragma unroll
                for (int c = 0; c < 8; c++) acc[j][c] += a[j] * b[c];
        }
        __syncthreads();
    }
#pragma unroll
    for (int j = 0; j < 8; j++) {
        int row = r0 + rg * 8 + j;
        if (row < nrows) {
            *(float4*)(out + (size_t)row * FEAT + cg * 8) =
                make_float4(acc[j][0], acc[j][1], acc[j][2], acc[j][3]);
            *(float4*)(out + (size_t)row * FEAT + cg * 8 + 4) =
                make_float4(acc[j][4], acc[j][5], acc[j][6], acc[j][7]);
        }
    }
}

// ---------------------------------------------------------------------------
// Per-node attention-score halves: ssrc/sdst laid out [N][4] (one float4/node)
// ---------------------------------------------------------------------------
__global__ __launch_bounds__(128) void scores_kernel(const float* __restrict__ xw,
                                                     const float* __restrict__ a_s,
                                                     const float* __restrict__ a_d,
                                                     float* __restrict__ ssrc,
                                                     float* __restrict__ sdst) {
    int n = blockIdx.x;
    int t = threadIdx.x;
    float v = xw[(size_t)n * FEAT + t];
    int h = t >> 5;
    float ps = v * a_s[t];
    float pd = v * a_d[t];
#pragma unroll
    for (int m = 16; m >= 1; m >>= 1) {
        ps += __shfl_xor(ps, m);
        pd += __shfl_xor(pd, m);
    }
    if ((t & 31) == 0) {
        ssrc[n * HEADS + h] = ps;
        sdst[n * HEADS + h] = pd;
    }
}

// ---------------------------------------------------------------------------
// Per-edge leaky-relu scores: sc[e][h] = leaky(ssrc[src[e]][h] + sdst[dst[e]][h])
// Edge-parallel, float4 gathers (16B), coalesced store.
// ---------------------------------------------------------------------------
__global__ void edge_scores(const float4* __restrict__ ssrc4,
                            const float4* __restrict__ sdst4,
                            const int* __restrict__ ssorted,
                            const int* __restrict__ dsorted,
                            float4* __restrict__ sc, int EP) {
    int e = blockIdx.x * 256 + threadIdx.x;
    if (e >= EP) return;
    float4 a = ssrc4[ssorted[e]];
    float4 b = sdst4[dsorted[e]];   // nearly sorted -> coalesced-ish
    float4 r;
    r.x = a.x + b.x; r.x = r.x > 0.f ? r.x : SLOPE * r.x;
    r.y = a.y + b.y; r.y = r.y > 0.f ? r.y : SLOPE * r.y;
    r.z = a.z + b.z; r.z = r.z > 0.f ? r.z : SLOPE * r.z;
    r.w = a.w + b.w; r.w = r.w > 0.f ? r.w : SLOPE * r.w;
    sc[e] = r;
}

// ---------------------------------------------------------------------------
// Edge softmax + aggregate, one 128-thread block per dst node.
// Pass 1: ONLINE max+den per head over coalesced sc reads (single pass).
// Pass 2: 32-edge chunks: weights from sc (coalesced) into LDS, then gather
//         xw with 4 edges concurrently, float4 per lane.
// ---------------------------------------------------------------------------
__global__ __launch_bounds__(128) void edge_agg(const float* __restrict__ xw,
                                                const float* __restrict__ sc,
                                                const int* __restrict__ rowptr,
                                                const int* __restrict__ ssorted,
                                                const float* __restrict__ bias,
                                                float* __restrict__ out,
                                                int final_layer) {
    int n = blockIdx.x;
    int t = threadIdx.x;
    int beg = rowptr[n], end = rowptr[n + 1];

    __shared__ float mh[HEADS], invh[HEADS];
    __shared__ float wbuf[32][HEADS];
    __shared__ int   sbuf[32];
    __shared__ float red[128][4];

    // ---- pass 1: online softmax stats per head
    {
        int h = t >> 5, lane = t & 31;
        float m = -1e30f, den = 0.f;
        for (int e = beg + lane; e < end; e += 32) {
            float s = sc[e * HEADS + h];
            if (s > m) { den = den * __expf(m - s) + 1.f; m = s; }
            else       { den += __expf(s - m); }
        }
#pragma unroll
        for (int k = 16; k >= 1; k >>= 1) {
            float mo = __shfl_xor(m, k), dn = __shfl_xor(den, k);
            float mn = fmaxf(m, mo);
            den = den * __expf(m - mn) + dn * __expf(mo - mn);
            m = mn;
        }
        if (lane == 0) { mh[h] = m; invh[h] = 1.f / den; }
    }
    __syncthreads();

    // ---- pass 2: chunked weight compute + 4-edge-parallel float4 gather
    int j = t >> 5;        // edge slot 0..3
    int q = t & 31;        // channel quad (channels 4q..4q+3)
    int qh = q >> 3;       // head owning this quad
    float4 acc = make_float4(0.f, 0.f, 0.f, 0.f);

    for (int cb = beg; cb < end; cb += 32) {
        int c = end - cb; if (c > 32) c = 32;
        {   // weights: thread (l = t/4, hh = t%4), coalesced sc reads
            int l = t >> 2, hh = t & 3;
            if (l < c) {
                if (hh == 0) sbuf[l] = ssorted[cb + l];
                float scv = sc[(cb + l) * HEADS + hh];
                wbuf[l][hh] = __expf(scv - mh[hh]) * invh[hh];
            }
        }
        __syncthreads();
        for (int i = j; i < c; i += 4) {
            int s = sbuf[i];
            float w = wbuf[i][qh];
            float4 v = *(const float4*)(xw + (size_t)s * FEAT + q * 4);
            acc.x += w * v.x; acc.y += w * v.y; acc.z += w * v.z; acc.w += w * v.w;
        }
        __syncthreads();
    }

    // ---- reduce over the 4 edge slots
    *(float4*)red[t] = acc;
    __syncthreads();

    if (!final_layer) {
        if (t < 32) {
            float4 r;
            r.x = red[t][0] + red[t + 32][0] + red[t + 64][0] + red[t + 96][0];
            r.y = red[t][1] + red[t + 32][1] + red[t + 64][1] + red[t + 96][1];
            r.z = red[t][2] + red[t + 32][2] + red[t + 64][2] + red[t + 96][2];
            r.w = red[t][3] + red[t + 32][3] + red[t + 64][3] + red[t + 96][3];
            const float4 b4 = *(const float4*)(bias + t * 4);
            r.x += b4.x; r.y += b4.y; r.z += b4.z; r.w += b4.w;
            r.x = r.x > 0.f ? r.x : expm1f(r.x);
            r.y = r.y > 0.f ? r.y : expm1f(r.y);
            r.z = r.z > 0.f ? r.z : expm1f(r.z);
            r.w = r.w > 0.f ? r.w : expm1f(r.w);
            *(float4*)(out + (size_t)n * FEAT + t * 4) = r;
        }
    } else {
        float4 r;
        if (t < 32) {
            r.x = red[t][0] + red[t + 32][0] + red[t + 64][0] + red[t + 96][0];
            r.y = red[t][1] + red[t + 32][1] + red[t + 64][1] + red[t + 96][1];
            r.z = red[t][2] + red[t + 32][2] + red[t + 64][2] + red[t + 96][2];
            r.w = red[t][3] + red[t + 32][3] + red[t + 64][3] + red[t + 96][3];
        }
        __syncthreads();
        if (t < 32) *(float4*)red[t] = r;
        __syncthreads();
        if (t < 8) {
            // head-mean: channel c (0..31) lives at quad h*8 + c/4
            float4 o;
            o.x = (red[t][0] + red[t + 8][0] + red[t + 16][0] + red[t + 24][0]) * 0.25f;
            o.y = (red[t][1] + red[t + 8][1] + red[t + 16][1] + red[t + 24][1]) * 0.25f;
            o.z = (red[t][2] + red[t + 8][2] + red[t + 16][2] + red[t + 24][2]) * 0.25f;
            o.w = (red[t][3] + red[t + 8][3] + red[t + 16][3] + red[t + 24][3]) * 0.25f;
            const float4 b4 = *(const float4*)(bias + t * 4);
            o.x += b4.x; o.y += b4.y; o.z += b4.z; o.w += b4.w;
            *(float4*)(out + (size_t)n * HID + t * 4) = o;
        }
    }
}

// ---------------------------------------------------------------------------
// Launch
// ---------------------------------------------------------------------------
extern "C" void kernel_launch(void* const* d_in, const int* in_sizes, int n_in,
                              void* d_out, int out_size, void* d_ws, size_t ws_size,
                              hipStream_t stream) {
    const float* x   = (const float*)d_in[0];
    const int* eidx  = (const int*)d_in[1];
    const float* W1  = (const float*)d_in[2];
    const float* as1 = (const float*)d_in[3];
    const float* ad1 = (const float*)d_in[4];
    const float* b1  = (const float*)d_in[5];
    const float* W2  = (const float*)d_in[6];
    const float* as2 = (const float*)d_in[7];
    const float* ad2 = (const float*)d_in[8];
    const float* b2  = (const float*)d_in[9];
    const float* W3  = (const float*)d_in[10];
    const float* as3 = (const float*)d_in[11];
    const float* ad3 = (const float*)d_in[12];
    const float* b3  = (const float*)d_in[13];

    const int Nn = in_sizes[0] / FEAT;   // 100000
    const int E  = in_sizes[1] / 2;      // 1200000
    const int EP = E + Nn;

    char* w = (char*)d_ws;
    size_t off = 0;
    auto alloc = [&](size_t bytes) {
        void* p = w + off;
        off += (bytes + 255) & ~(size_t)255;
        return p;
    };
    float* bufA   = (float*)alloc((size_t)Nn * FEAT * 4);
    float* bufB   = (float*)alloc((size_t)Nn * FEAT * 4);
    float* ssrc   = (float*)alloc((size_t)Nn * HEADS * 4);
    float* sdst   = (float*)alloc((size_t)Nn * HEADS * 4);
    float* scbuf  = (float*)alloc((size_t)EP * HEADS * 4);
    int*   rowptr = (int*)alloc((size_t)(Nn + 1) * 4);
    int*   cursor = (int*)alloc((size_t)Nn * 4);
    int*   deg    = (int*)alloc((size_t)Nn * 4);
    int*   ssort  = (int*)alloc((size_t)EP * 4);
    int*   dsort  = (int*)alloc((size_t)EP * 4);
    int*   bsum   = (int*)alloc(64 * 4);
    (void)ws_size;

    // ---- CSR build (once; shared by all 3 layers)
    hipMemsetAsync(deg, 0, (size_t)Nn * 4, stream);
    hist_kernel<<<(E + 255) / 256, 256, 0, stream>>>(eidx, deg, E);
    int nscan = (Nn + SCAN_TILE - 1) / SCAN_TILE;   // 25 (<= 64)
    scan_partial<<<nscan, SCAN_BLK, 0, stream>>>(deg, bsum, Nn);
    scan_bsum<<<1, 64, 0, stream>>>(bsum, nscan);
    scan_final<<<nscan, SCAN_BLK, 0, stream>>>(deg, bsum, rowptr, cursor, Nn);
    scatter_kernel<<<(EP + 255) / 256, 256, 0, stream>>>(eidx, cursor, ssort, dsort, E, Nn);

    int gemm_grid = (Nn + GBM - 1) / GBM;
    int escore_grid = (EP + 255) / 256;

    // ---- layer 1
    gemm128<<<gemm_grid, 256, 0, stream>>>(x, W1, bufA, Nn);
    scores_kernel<<<Nn, 128, 0, stream>>>(bufA, as1, ad1, ssrc, sdst);
    edge_scores<<<escore_grid, 256, 0, stream>>>((const float4*)ssrc, (const float4*)sdst,
                                                 ssort, dsort, (float4*)scbuf, EP);
    edge_agg<<<Nn, 128, 0, stream>>>(bufA, scbuf, rowptr, ssort, b1, bufB, 0);

    // ---- layer 2
    gemm128<<<gemm_grid, 256, 0, stream>>>(bufB, W2, bufA, Nn);
    scores_kernel<<<Nn, 128, 0, stream>>>(bufA, as2, ad2, ssrc, sdst);
    edge_scores<<<escore_grid, 256, 0, stream>>>((const float4*)ssrc, (const float4*)sdst,
                                                 ssort, dsort, (float4*)scbuf, EP);
    edge_agg<<<Nn, 128, 0, stream>>>(bufA, scbuf, rowptr, ssort, b2, bufB, 0);

    // ---- layer 3 (mean over heads, no ELU)
    gemm128<<<gemm_grid, 256, 0, stream>>>(bufB, W3, bufA, Nn);
    scores_kernel<<<Nn, 128, 0, stream>>>(bufA, as3, ad3, ssrc, sdst);
    edge_scores<<<escore_grid, 256, 0, stream>>>((const float4*)ssrc, (const float4*)sdst,
                                                 ssort, dsort, (float4*)scbuf, EP);
    edge_agg<<<Nn, 128, 0, stream>>>(bufA, scbuf, rowptr, ssort, b3, (float*)d_out, 1);
}

// Round 5
// 810.533 us; speedup vs baseline: 1.5813x; 1.0503x over previous
//
#include <hip/hip_runtime.h>
#include <math.h>

#define HEADS 4
#define HID 32
#define FEAT 128   // HEADS*HID == IN == hidden width everywhere
#define SLOPE 0.2f

typedef __attribute__((ext_vector_type(8))) short  frag_ab;  // 8 bf16 (4 VGPRs)
typedef __attribute__((ext_vector_type(4))) float  frag_cd;  // 4 fp32

__device__ inline unsigned short f2bf(float f) {            // RNE fp32->bf16 bits
    unsigned u = __float_as_uint(f);
    unsigned r = u + 0x7FFFu + ((u >> 16) & 1u);
    return (unsigned short)(r >> 16);
}
__device__ inline float bf2f(unsigned short b) {
    return __uint_as_float(((unsigned)b) << 16);
}

// ---------------------------------------------------------------------------
// CSR build
// ---------------------------------------------------------------------------

__global__ void hist_kernel(const int* __restrict__ edge_index, int* __restrict__ deg, int E) {
    int e = blockIdx.x * 256 + threadIdx.x;
    if (e < E) atomicAdd(&deg[edge_index[E + e]], 1);
}

#define SCAN_BLK 1024
#define SCAN_CHUNK 4
#define SCAN_TILE (SCAN_BLK * SCAN_CHUNK)

__global__ __launch_bounds__(SCAN_BLK) void scan_partial(const int* __restrict__ deg,
                                                         int* __restrict__ bsum, int Nn) {
    __shared__ int red[SCAN_BLK];
    int t = threadIdx.x;
    int base = blockIdx.x * SCAN_TILE + t * SCAN_CHUNK;
    int s = 0;
#pragma unroll
    for (int i = 0; i < SCAN_CHUNK; i++) {
        int idx = base + i;
        if (idx < Nn) s += deg[idx] + 1;
    }
    red[t] = s;
    __syncthreads();
    for (int off = SCAN_BLK / 2; off >= 1; off >>= 1) {
        if (t < off) red[t] += red[t + off];
        __syncthreads();
    }
    if (t == 0) bsum[blockIdx.x] = red[0];
}

__global__ __launch_bounds__(64) void scan_bsum(int* __restrict__ bsum, int nb) {
    int t = threadIdx.x;
    int v = (t < nb) ? bsum[t] : 0;
    int orig = v;
#pragma unroll
    for (int off = 1; off < 64; off <<= 1) {
        int u = __shfl_up(v, off);
        if (t >= off) v += u;
    }
    if (t < nb) bsum[t] = v - orig;
}

__global__ __launch_bounds__(SCAN_BLK) void scan_final(const int* __restrict__ deg,
                                                       const int* __restrict__ bsum,
                                                       int* __restrict__ rowptr,
                                                       int* __restrict__ cursor, int Nn) {
    __shared__ int sums[SCAN_BLK];
    int t = threadIdx.x;
    int base = blockIdx.x * SCAN_TILE + t * SCAN_CHUNK;
    int loc[SCAN_CHUNK];
    int s = 0;
#pragma unroll
    for (int i = 0; i < SCAN_CHUNK; i++) {
        int idx = base + i;
        int d = (idx < Nn) ? deg[idx] + 1 : 0;
        loc[i] = s;
        s += d;
    }
    sums[t] = s;
    __syncthreads();
    for (int off = 1; off < SCAN_BLK; off <<= 1) {
        int v = (t >= off) ? sums[t - off] : 0;
        __syncthreads();
        sums[t] += v;
        __syncthreads();
    }
    int texcl = (t == 0) ? 0 : sums[t - 1];
    int offn = bsum[blockIdx.x] + texcl;
#pragma unroll
    for (int i = 0; i < SCAN_CHUNK; i++) {
        int idx = base + i;
        if (idx < Nn) {
            int v = offn + loc[i];
            rowptr[idx] = v;
            cursor[idx] = v;
        }
    }
    if (blockIdx.x == gridDim.x - 1 && t == SCAN_BLK - 1)
        rowptr[Nn] = offn + s;
}

__global__ void scatter_kernel(const int* __restrict__ edge_index, int* __restrict__ cursor,
                               int* __restrict__ ssorted, int* __restrict__ dsorted,
                               int E, int Nn) {
    int e = blockIdx.x * 256 + threadIdx.x;
    if (e < E) {
        int d = edge_index[E + e];
        int srcv = edge_index[e];
        int pos = atomicAdd(&cursor[d], 1);
        ssorted[pos] = srcv;
        dsorted[pos] = d;
    } else if (e < E + Nn) {
        int i = e - E;
        int pos = atomicAdd(&cursor[i], 1);
        ssorted[pos] = i;
        dsorted[pos] = i;
    }
}

// ---------------------------------------------------------------------------
// W prep: split fp32 W[k][c] into bf16 hi/lo, transposed + fragment-friendly:
// wt[(g*128 + c)*8 + j] = W[g*8 + j][c]   (g = k/8). A lane's 16B frag read at
// (c, k0+q*8) is then contiguous, and lanes 0..15 (consecutive c) coalesce.
// ---------------------------------------------------------------------------
__global__ void prep_w(const float* __restrict__ W,
                       unsigned short* __restrict__ wt_hi,
                       unsigned short* __restrict__ wt_lo) {
    int idx = blockIdx.x * 256 + threadIdx.x;   // 16384
    if (idx >= FEAT * FEAT) return;
    int c = idx >> 7, k = idx & 127;
    float v = W[(size_t)k * FEAT + c];
    unsigned short hi = f2bf(v);
    unsigned short lo = f2bf(v - bf2f(hi));
    int g = k >> 3, j = k & 7;
    wt_hi[((size_t)g * FEAT + c) * 8 + j] = hi;
    wt_lo[((size_t)g * FEAT + c) * 8 + j] = lo;
}

// ---------------------------------------------------------------------------
// GEMM via MFMA 16x16x32 bf16, split hi/lo for fp32-level accuracy.
// Block = 256 threads (4 waves), 64 rows x 128 cols; wave = 16 rows x 128 cols
// (8 col-tiles). A frags load direct from global (each element read once),
// W frags from the L2-resident prepped layout. D = Ahi*Whi + Ahi*Wlo + Alo*Whi.
// ---------------------------------------------------------------------------
__global__ __launch_bounds__(256) void gemm_mfma(const float* __restrict__ A,
                                                 const unsigned short* __restrict__ wt_hi,
                                                 const unsigned short* __restrict__ wt_lo,
                                                 float* __restrict__ out, int nrows) {
    int tid = threadIdx.x;
    int wave = tid >> 6, lane = tid & 63;
    int r = lane & 15;     // A-row / D-col index within tile
    int q = lane >> 4;     // k-quad (A/B), row-quad (D)
    int rowbase = blockIdx.x * 64 + wave * 16;

    int arow = rowbase + r;
    if (arow >= nrows) arow = nrows - 1;   // clamp loads; stores guarded

    frag_cd acc[8];
#pragma unroll
    for (int ct = 0; ct < 8; ct++) acc[ct] = (frag_cd){0.f, 0.f, 0.f, 0.f};

    const float* arowp = A + (size_t)arow * FEAT;

#pragma unroll
    for (int k0 = 0; k0 < FEAT; k0 += 32) {
        int kk = k0 + q * 8;
        float4 a0 = *(const float4*)(arowp + kk);
        float4 a1 = *(const float4*)(arowp + kk + 4);
        float av[8] = {a0.x, a0.y, a0.z, a0.w, a1.x, a1.y, a1.z, a1.w};
        frag_ab ahi, alo;
#pragma unroll
        for (int j = 0; j < 8; j++) {
            unsigned short h = f2bf(av[j]);
            ahi[j] = (short)h;
            alo[j] = (short)f2bf(av[j] - bf2f(h));
        }
        int g = kk >> 3;   // fragment group index
#pragma unroll
        for (int ct = 0; ct < 8; ct++) {
            int c = ct * 16 + r;
            const frag_ab bhi = *(const frag_ab*)(wt_hi + ((size_t)g * FEAT + c) * 8);
            const frag_ab blo = *(const frag_ab*)(wt_lo + ((size_t)g * FEAT + c) * 8);
            acc[ct] = __builtin_amdgcn_mfma_f32_16x16x32_bf16(ahi, bhi, acc[ct], 0, 0, 0);
            acc[ct] = __builtin_amdgcn_mfma_f32_16x16x32_bf16(ahi, blo, acc[ct], 0, 0, 0);
            acc[ct] = __builtin_amdgcn_mfma_f32_16x16x32_bf16(alo, bhi, acc[ct], 0, 0, 0);
        }
    }

    // C/D layout: col = lane&15, row = q*4 + reg  [m89-verified]
#pragma unroll
    for (int ct = 0; ct < 8; ct++) {
#pragma unroll
        for (int gi = 0; gi < 4; gi++) {
            int rr = rowbase + q * 4 + gi;
            if (rr < nrows)
                out[(size_t)rr * FEAT + ct * 16 + r] = acc[ct][gi];
        }
    }
}

// ---------------------------------------------------------------------------
// Per-node attention-score halves: ssrc/sdst laid out [N][4]
// ---------------------------------------------------------------------------
__global__ __launch_bounds__(128) void scores_kernel(const float* __restrict__ xw,
                                                     const float* __restrict__ a_s,
                                                     const float* __restrict__ a_d,
                                                     float* __restrict__ ssrc,
                                                     float* __restrict__ sdst) {
    int n = blockIdx.x;
    int t = threadIdx.x;
    float v = xw[(size_t)n * FEAT + t];
    int h = t >> 5;
    float ps = v * a_s[t];
    float pd = v * a_d[t];
#pragma unroll
    for (int m = 16; m >= 1; m >>= 1) {
        ps += __shfl_xor(ps, m);
        pd += __shfl_xor(pd, m);
    }
    if ((t & 31) == 0) {
        ssrc[n * HEADS + h] = ps;
        sdst[n * HEADS + h] = pd;
    }
}

// ---------------------------------------------------------------------------
// Per-edge leaky-relu scores (edge-parallel)
// ---------------------------------------------------------------------------
__global__ void edge_scores(const float4* __restrict__ ssrc4,
                            const float4* __restrict__ sdst4,
                            const int* __restrict__ ssorted,
                            const int* __restrict__ dsorted,
                            float4* __restrict__ sc, int EP) {
    int e = blockIdx.x * 256 + threadIdx.x;
    if (e >= EP) return;
    float4 a = ssrc4[ssorted[e]];
    float4 b = sdst4[dsorted[e]];
    float4 r;
    r.x = a.x + b.x; r.x = r.x > 0.f ? r.x : SLOPE * r.x;
    r.y = a.y + b.y; r.y = r.y > 0.f ? r.y : SLOPE * r.y;
    r.z = a.z + b.z; r.z = r.z > 0.f ? r.z : SLOPE * r.z;
    r.w = a.w + b.w; r.w = r.w > 0.f ? r.w : SLOPE * r.w;
    sc[e] = r;
}

// ---------------------------------------------------------------------------
// Softmax stats: one thread per (node, head); serial online max/den over row.
// ---------------------------------------------------------------------------
__global__ void stats_kernel(const float* __restrict__ sc,
                             const int* __restrict__ rowptr,
                             float* __restrict__ mbuf, float* __restrict__ ibuf, int Nn) {
    int idx = blockIdx.x * 256 + threadIdx.x;
    if (idx >= Nn * HEADS) return;
    int n = idx >> 2, h = idx & 3;
    int beg = rowptr[n], end = rowptr[n + 1];
    float m = -1e30f, den = 0.f;
    for (int e = beg; e < end; e++) {
        float s = sc[e * HEADS + h];
        if (s > m) { den = den * __expf(m - s) + 1.f; m = s; }
        else       { den += __expf(s - m); }
    }
    mbuf[idx] = m;
    ibuf[idx] = 1.f / den;   // den >= 1 (self loop guarantees a max edge)
}

// ---------------------------------------------------------------------------
// Weights: edge-parallel, sc overwritten in place with final attn weight.
// ---------------------------------------------------------------------------
__global__ void weights_kernel(float4* __restrict__ sc,
                               const float4* __restrict__ m4,
                               const float4* __restrict__ i4,
                               const int* __restrict__ dsorted, int EP) {
    int e = blockIdx.x * 256 + threadIdx.x;
    if (e >= EP) return;
    int d = dsorted[e];
    float4 s = sc[e], m = m4[d], iv = i4[d];
    float4 w;
    w.x = __expf(s.x - m.x) * iv.x;
    w.y = __expf(s.y - m.y) * iv.y;
    w.z = __expf(s.z - m.z) * iv.z;
    w.w = __expf(s.w - m.w) * iv.w;
    sc[e] = w;
}

// ---------------------------------------------------------------------------
// Aggregate: pure gather-accumulate per dst node (no softmax math left).
// Thread = (edge-slot j=t/32, channel-quad q=t%32); 32-edge chunks.
// ---------------------------------------------------------------------------
__global__ __launch_bounds__(128) void edge_agg(const float* __restrict__ xw,
                                                const float* __restrict__ wgt,
                                                const int* __restrict__ rowptr,
                                                const int* __restrict__ ssorted,
                                                const float* __restrict__ bias,
                                                float* __restrict__ out,
                                                int final_layer) {
    int n = blockIdx.x;
    int t = threadIdx.x;
    int beg = rowptr[n], end = rowptr[n + 1];

    __shared__ float wbuf[32][HEADS];
    __shared__ int   sbuf[32];
    __shared__ float red[128][4];

    int j = t >> 5;        // edge slot 0..3
    int q = t & 31;        // channel quad
    int qh = q >> 3;       // head of this quad
    float4 acc = make_float4(0.f, 0.f, 0.f, 0.f);

    for (int cb = beg; cb < end; cb += 32) {
        int c = end - cb; if (c > 32) c = 32;
        if (t < c) sbuf[t] = ssorted[cb + t];
        {
            int l = t >> 2, hh = t & 3;
            if (l < c) wbuf[l][hh] = wgt[(cb + l) * HEADS + hh];
        }
        __syncthreads();
        for (int i = j; i < c; i += 4) {
            int s = sbuf[i];
            float w = wbuf[i][qh];
            float4 v = *(const float4*)(xw + (size_t)s * FEAT + q * 4);
            acc.x += w * v.x; acc.y += w * v.y; acc.z += w * v.z; acc.w += w * v.w;
        }
        __syncthreads();
    }

    *(float4*)red[t] = acc;
    __syncthreads();

    if (!final_layer) {
        if (t < 32) {
            float4 r;
            r.x = red[t][0] + red[t + 32][0] + red[t + 64][0] + red[t + 96][0];
            r.y = red[t][1] + red[t + 32][1] + red[t + 64][1] + red[t + 96][1];
            r.z = red[t][2] + red[t + 32][2] + red[t + 64][2] + red[t + 96][2];
            r.w = red[t][3] + red[t + 32][3] + red[t + 64][3] + red[t + 96][3];
            const float4 b4 = *(const float4*)(bias + t * 4);
            r.x += b4.x; r.y += b4.y; r.z += b4.z; r.w += b4.w;
            r.x = r.x > 0.f ? r.x : expm1f(r.x);
            r.y = r.y > 0.f ? r.y : expm1f(r.y);
            r.z = r.z > 0.f ? r.z : expm1f(r.z);
            r.w = r.w > 0.f ? r.w : expm1f(r.w);
            *(float4*)(out + (size_t)n * FEAT + t * 4) = r;
        }
    } else {
        float4 r;
        if (t < 32) {
            r.x = red[t][0] + red[t + 32][0] + red[t + 64][0] + red[t + 96][0];
            r.y = red[t][1] + red[t + 32][1] + red[t + 64][1] + red[t + 96][1];
            r.z = red[t][2] + red[t + 32][2] + red[t + 64][2] + red[t + 96][2];
            r.w = red[t][3] + red[t + 32][3] + red[t + 64][3] + red[t + 96][3];
        }
        __syncthreads();
        if (t < 32) *(float4*)red[t] = r;
        __syncthreads();
        if (t < 8) {
            float4 o;
            o.x = (red[t][0] + red[t + 8][0] + red[t + 16][0] + red[t + 24][0]) * 0.25f;
            o.y = (red[t][1] + red[t + 8][1] + red[t + 16][1] + red[t + 24][1]) * 0.25f;
            o.z = (red[t][2] + red[t + 8][2] + red[t + 16][2] + red[t + 24][2]) * 0.25f;
            o.w = (red[t][3] + red[t + 8][3] + red[t + 16][3] + red[t + 24][3]) * 0.25f;
            const float4 b4 = *(const float4*)(bias + t * 4);
            o.x += b4.x; o.y += b4.y; o.z += b4.z; o.w += b4.w;
            *(float4*)(out + (size_t)n * HID + t * 4) = o;
        }
    }
}

// ---------------------------------------------------------------------------
// Launch
// ---------------------------------------------------------------------------
extern "C" void kernel_launch(void* const* d_in, const int* in_sizes, int n_in,
                              void* d_out, int out_size, void* d_ws, size_t ws_size,
                              hipStream_t stream) {
    const float* x   = (const float*)d_in[0];
    const int* eidx  = (const int*)d_in[1];
    const float* W1  = (const float*)d_in[2];
    const float* as1 = (const float*)d_in[3];
    const float* ad1 = (const float*)d_in[4];
    const float* b1  = (const float*)d_in[5];
    const float* W2  = (const float*)d_in[6];
    const float* as2 = (const float*)d_in[7];
    const float* ad2 = (const float*)d_in[8];
    const float* b2  = (const float*)d_in[9];
    const float* W3  = (const float*)d_in[10];
    const float* as3 = (const float*)d_in[11];
    const float* ad3 = (const float*)d_in[12];
    const float* b3  = (const float*)d_in[13];

    const int Nn = in_sizes[0] / FEAT;   // 100000
    const int E  = in_sizes[1] / 2;      // 1200000
    const int EP = E + Nn;

    char* w = (char*)d_ws;
    size_t off = 0;
    auto alloc = [&](size_t bytes) {
        void* p = w + off;
        off += (bytes + 255) & ~(size_t)255;
        return p;
    };
    float* bufA   = (float*)alloc((size_t)Nn * FEAT * 4);
    float* bufB   = (float*)alloc((size_t)Nn * FEAT * 4);
    float* ssrc   = (float*)alloc((size_t)Nn * HEADS * 4);
    float* sdst   = (float*)alloc((size_t)Nn * HEADS * 4);
    float* scbuf  = (float*)alloc((size_t)EP * HEADS * 4);
    float* mbuf   = (float*)alloc((size_t)Nn * HEADS * 4);
    float* ibuf   = (float*)alloc((size_t)Nn * HEADS * 4);
    int*   rowptr = (int*)alloc((size_t)(Nn + 1) * 4);
    int*   cursor = (int*)alloc((size_t)Nn * 4);
    int*   deg    = (int*)alloc((size_t)Nn * 4);
    int*   ssort  = (int*)alloc((size_t)EP * 4);
    int*   dsort  = (int*)alloc((size_t)EP * 4);
    int*   bsum   = (int*)alloc(64 * 4);
    unsigned short* wth = (unsigned short*)alloc((size_t)FEAT * FEAT * 2);
    unsigned short* wtl = (unsigned short*)alloc((size_t)FEAT * FEAT * 2);
    (void)ws_size;

    // ---- CSR build (once; shared by all 3 layers)
    hipMemsetAsync(deg, 0, (size_t)Nn * 4, stream);
    hist_kernel<<<(E + 255) / 256, 256, 0, stream>>>(eidx, deg, E);
    int nscan = (Nn + SCAN_TILE - 1) / SCAN_TILE;
    scan_partial<<<nscan, SCAN_BLK, 0, stream>>>(deg, bsum, Nn);
    scan_bsum<<<1, 64, 0, stream>>>(bsum, nscan);
    scan_final<<<nscan, SCAN_BLK, 0, stream>>>(deg, bsum, rowptr, cursor, Nn);
    scatter_kernel<<<(EP + 255) / 256, 256, 0, stream>>>(eidx, cursor, ssort, dsort, E, Nn);

    const int gemm_grid = (Nn + 63) / 64;
    const int eg  = (EP + 255) / 256;
    const int sg  = (Nn * HEADS + 255) / 256;
    const int wpg = (FEAT * FEAT + 255) / 256;

    const float* Ws[3] = {W1, W2, W3};
    const float* as[3] = {as1, as2, as3};
    const float* ad[3] = {ad1, ad2, ad3};
    const float* bs[3] = {b1, b2, b3};

    const float* cur_in = x;
    for (int L = 0; L < 3; L++) {
        float* xw = bufA;
        float* nxt = (L == 2) ? (float*)d_out : bufB;
        prep_w<<<wpg, 256, 0, stream>>>(Ws[L], wth, wtl);
        gemm_mfma<<<gemm_grid, 256, 0, stream>>>(cur_in, wth, wtl, xw, Nn);
        scores_kernel<<<Nn, 128, 0, stream>>>(xw, as[L], ad[L], ssrc, sdst);
        edge_scores<<<eg, 256, 0, stream>>>((const float4*)ssrc, (const float4*)sdst,
                                            ssort, dsort, (float4*)scbuf, EP);
        stats_kernel<<<sg, 256, 0, stream>>>(scbuf, rowptr, mbuf, ibuf, Nn);
        weights_kernel<<<eg, 256, 0, stream>>>((float4*)scbuf, (const float4*)mbuf,
                                               (const float4*)ibuf, dsort, EP);
        edge_agg<<<Nn, 128, 0, stream>>>(xw, scbuf, rowptr, ssort, bs[L], nxt, L == 2);
        cur_in = bufB;
    }
}

// Round 6
// 792.995 us; speedup vs baseline: 1.6162x; 1.0221x over previous
//
#include <hip/hip_runtime.h>
#include <math.h>

#define HEADS 4
#define HID 32
#define FEAT 128   // HEADS*HID == IN == hidden width everywhere
#define SLOPE 0.2f

typedef __attribute__((ext_vector_type(8))) short          frag_ab;  // 8 bf16
typedef __attribute__((ext_vector_type(4))) float          frag_cd;  // 4 fp32
typedef __attribute__((ext_vector_type(8))) unsigned short u16x8;

__device__ inline unsigned short f2bf(float f) {            // RNE fp32->bf16 bits
    unsigned u = __float_as_uint(f);
    unsigned r = u + 0x7FFFu + ((u >> 16) & 1u);
    return (unsigned short)(r >> 16);
}
__device__ inline float bf2f(unsigned short b) {
    return __uint_as_float(((unsigned)b) << 16);
}

// ---------------------------------------------------------------------------
// CSR build
// ---------------------------------------------------------------------------

__global__ void hist_kernel(const int* __restrict__ edge_index, int* __restrict__ deg, int E) {
    int e = blockIdx.x * 256 + threadIdx.x;
    if (e < E) atomicAdd(&deg[edge_index[E + e]], 1);
}

#define SCAN_BLK 1024
#define SCAN_CHUNK 4
#define SCAN_TILE (SCAN_BLK * SCAN_CHUNK)

__global__ __launch_bounds__(SCAN_BLK) void scan_partial(const int* __restrict__ deg,
                                                         int* __restrict__ bsum, int Nn) {
    __shared__ int red[SCAN_BLK];
    int t = threadIdx.x;
    int base = blockIdx.x * SCAN_TILE + t * SCAN_CHUNK;
    int s = 0;
#pragma unroll
    for (int i = 0; i < SCAN_CHUNK; i++) {
        int idx = base + i;
        if (idx < Nn) s += deg[idx] + 1;
    }
    red[t] = s;
    __syncthreads();
    for (int off = SCAN_BLK / 2; off >= 1; off >>= 1) {
        if (t < off) red[t] += red[t + off];
        __syncthreads();
    }
    if (t == 0) bsum[blockIdx.x] = red[0];
}

__global__ __launch_bounds__(64) void scan_bsum(int* __restrict__ bsum, int nb) {
    int t = threadIdx.x;
    int v = (t < nb) ? bsum[t] : 0;
    int orig = v;
#pragma unroll
    for (int off = 1; off < 64; off <<= 1) {
        int u = __shfl_up(v, off);
        if (t >= off) v += u;
    }
    if (t < nb) bsum[t] = v - orig;
}

__global__ __launch_bounds__(SCAN_BLK) void scan_final(const int* __restrict__ deg,
                                                       const int* __restrict__ bsum,
                                                       int* __restrict__ rowptr,
                                                       int* __restrict__ cursor, int Nn) {
    __shared__ int sums[SCAN_BLK];
    int t = threadIdx.x;
    int base = blockIdx.x * SCAN_TILE + t * SCAN_CHUNK;
    int loc[SCAN_CHUNK];
    int s = 0;
#pragma unroll
    for (int i = 0; i < SCAN_CHUNK; i++) {
        int idx = base + i;
        int d = (idx < Nn) ? deg[idx] + 1 : 0;
        loc[i] = s;
        s += d;
    }
    sums[t] = s;
    __syncthreads();
    for (int off = 1; off < SCAN_BLK; off <<= 1) {
        int v = (t >= off) ? sums[t - off] : 0;
        __syncthreads();
        sums[t] += v;
        __syncthreads();
    }
    int texcl = (t == 0) ? 0 : sums[t - 1];
    int offn = bsum[blockIdx.x] + texcl;
#pragma unroll
    for (int i = 0; i < SCAN_CHUNK; i++) {
        int idx = base + i;
        if (idx < Nn) {
            int v = offn + loc[i];
            rowptr[idx] = v;
            cursor[idx] = v;
        }
    }
    if (blockIdx.x == gridDim.x - 1 && t == SCAN_BLK - 1)
        rowptr[Nn] = offn + s;
}

__global__ void scatter_kernel(const int* __restrict__ edge_index, int* __restrict__ cursor,
                               int* __restrict__ ssorted, int* __restrict__ dsorted,
                               int E, int Nn) {
    int e = blockIdx.x * 256 + threadIdx.x;
    if (e < E) {
        int d = edge_index[E + e];
        int srcv = edge_index[e];
        int pos = atomicAdd(&cursor[d], 1);
        ssorted[pos] = srcv;
        dsorted[pos] = d;
    } else if (e < E + Nn) {
        int i = e - E;
        int pos = atomicAdd(&cursor[i], 1);
        ssorted[pos] = i;
        dsorted[pos] = i;
    }
}

// ---------------------------------------------------------------------------
// W prep: split fp32 W[k][c] into bf16 hi/lo, fragment-friendly transposed:
// wt[(g*128 + c)*8 + j] = W[g*8 + j][c]   (g = k/8)
// ---------------------------------------------------------------------------
__global__ void prep_w(const float* __restrict__ W,
                       unsigned short* __restrict__ wt_hi,
                       unsigned short* __restrict__ wt_lo) {
    int idx = blockIdx.x * 256 + threadIdx.x;
    if (idx >= FEAT * FEAT) return;
    int c = idx >> 7, k = idx & 127;
    float v = W[(size_t)k * FEAT + c];
    unsigned short hi = f2bf(v);
    unsigned short lo = f2bf(v - bf2f(hi));
    int g = k >> 3, j = k & 7;
    wt_hi[((size_t)g * FEAT + c) * 8 + j] = hi;
    wt_lo[((size_t)g * FEAT + c) * 8 + j] = lo;
}

// ---------------------------------------------------------------------------
// GEMM via MFMA 16x16x32 bf16 (split hi/lo = fp32-level accuracy) with FUSED
// epilogue: writes bf16 feature matrix xwb AND per-node attn score halves.
// Block = 256 thr (4 waves), 64 rows; wave = 16 rows x 128 cols (8 col-tiles).
// ---------------------------------------------------------------------------
__global__ __launch_bounds__(256) void gemm_mfma(const float* __restrict__ A,
                                                 const unsigned short* __restrict__ wt_hi,
                                                 const unsigned short* __restrict__ wt_lo,
                                                 const float* __restrict__ a_s,
                                                 const float* __restrict__ a_d,
                                                 unsigned short* __restrict__ xwb,
                                                 float* __restrict__ ssrc,
                                                 float* __restrict__ sdst,
                                                 int nrows) {
    int tid = threadIdx.x;
    int wave = tid >> 6, lane = tid & 63;
    int r = lane & 15;     // A-row (load) / D-col (store) index within tile
    int q = lane >> 4;     // k-quad (A/B) / row-quad (D)
    int rowbase = blockIdx.x * 64 + wave * 16;

    int arow = rowbase + r;
    if (arow >= nrows) arow = nrows - 1;

    frag_cd acc[8];
#pragma unroll
    for (int ct = 0; ct < 8; ct++) acc[ct] = (frag_cd){0.f, 0.f, 0.f, 0.f};

    const float* arowp = A + (size_t)arow * FEAT;

#pragma unroll
    for (int k0 = 0; k0 < FEAT; k0 += 32) {
        int kk = k0 + q * 8;
        float4 a0 = *(const float4*)(arowp + kk);
        float4 a1 = *(const float4*)(arowp + kk + 4);
        float av[8] = {a0.x, a0.y, a0.z, a0.w, a1.x, a1.y, a1.z, a1.w};
        frag_ab ahi, alo;
#pragma unroll
        for (int j = 0; j < 8; j++) {
            unsigned short h = f2bf(av[j]);
            ahi[j] = (short)h;
            alo[j] = (short)f2bf(av[j] - bf2f(h));
        }
        int g = kk >> 3;
#pragma unroll
        for (int ct = 0; ct < 8; ct++) {
            int c = ct * 16 + r;
            const frag_ab bhi = *(const frag_ab*)(wt_hi + ((size_t)g * FEAT + c) * 8);
            const frag_ab blo = *(const frag_ab*)(wt_lo + ((size_t)g * FEAT + c) * 8);
            acc[ct] = __builtin_amdgcn_mfma_f32_16x16x32_bf16(ahi, bhi, acc[ct], 0, 0, 0);
            acc[ct] = __builtin_amdgcn_mfma_f32_16x16x32_bf16(ahi, blo, acc[ct], 0, 0, 0);
            acc[ct] = __builtin_amdgcn_mfma_f32_16x16x32_bf16(alo, bhi, acc[ct], 0, 0, 0);
        }
    }

    // attn vectors for this lane's 8 columns
    float asv[8], adv[8];
#pragma unroll
    for (int ct = 0; ct < 8; ct++) {
        asv[ct] = a_s[ct * 16 + r];
        adv[ct] = a_d[ct * 16 + r];
    }

    // epilogue: per row (q*4+gi): bf16 store + per-head score reduction.
    // D layout: col = ct*16 + r, row = q*4 + gi  [m89-verified]
#pragma unroll
    for (int gi = 0; gi < 4; gi++) {
        int rr = rowbase + q * 4 + gi;
        bool ok = rr < nrows;
        float ps[4] = {0.f, 0.f, 0.f, 0.f}, pd[4] = {0.f, 0.f, 0.f, 0.f};
#pragma unroll
        for (int ct = 0; ct < 8; ct++) {
            float v = acc[ct][gi];
            if (ok) xwb[(size_t)rr * FEAT + ct * 16 + r] = f2bf(v);
            ps[ct >> 1] += v * asv[ct];
            pd[ct >> 1] += v * adv[ct];
        }
#pragma unroll
        for (int h = 0; h < 4; h++) {
#pragma unroll
            for (int m = 1; m < 16; m <<= 1) {
                ps[h] += __shfl_xor(ps[h], m);
                pd[h] += __shfl_xor(pd[h], m);
            }
        }
        if (ok) {
            if (r < 4)           ssrc[rr * HEADS + r] = ps[r];
            else if (r < 8)      sdst[rr * HEADS + (r - 4)] = pd[r - 4];
        }
    }
}

// ---------------------------------------------------------------------------
// Per-edge leaky-relu scores (edge-parallel)
// ---------------------------------------------------------------------------
__global__ void edge_scores(const float4* __restrict__ ssrc4,
                            const float4* __restrict__ sdst4,
                            const int* __restrict__ ssorted,
                            const int* __restrict__ dsorted,
                            float4* __restrict__ sc, int EP) {
    int e = blockIdx.x * 256 + threadIdx.x;
    if (e >= EP) return;
    float4 a = ssrc4[ssorted[e]];
    float4 b = sdst4[dsorted[e]];
    float4 r;
    r.x = a.x + b.x; r.x = r.x > 0.f ? r.x : SLOPE * r.x;
    r.y = a.y + b.y; r.y = r.y > 0.f ? r.y : SLOPE * r.y;
    r.z = a.z + b.z; r.z = r.z > 0.f ? r.z : SLOPE * r.z;
    r.w = a.w + b.w; r.w = r.w > 0.f ? r.w : SLOPE * r.w;
    sc[e] = r;
}

// ---------------------------------------------------------------------------
// Softmax stats + weights fused: one thread per (node, head). Pass 1: online
// max/den over the row. Pass 2: overwrite sc in place with the final weight.
// ---------------------------------------------------------------------------
__global__ void stats_weights(float* __restrict__ sc,
                              const int* __restrict__ rowptr, int Nn) {
    int idx = blockIdx.x * 256 + threadIdx.x;
    if (idx >= Nn * HEADS) return;
    int n = idx >> 2, h = idx & 3;
    int beg = rowptr[n], end = rowptr[n + 1];
    float m = -1e30f, den = 0.f;
    for (int e = beg; e < end; e++) {
        float s = sc[e * HEADS + h];
        if (s > m) { den = den * __expf(m - s) + 1.f; m = s; }
        else       { den += __expf(s - m); }
    }
    float inv = 1.f / den;
    for (int e = beg; e < end; e++)
        sc[e * HEADS + h] = __expf(sc[e * HEADS + h] - m) * inv;
}

// ---------------------------------------------------------------------------
// Aggregate: pure gather-accumulate, bf16 messages. One 128-thread block per
// dst node. Thread = (edge-slot j=t/16 of 8, channel-octet q=t%16); 16B
// ushort8 gathers, fp32 accumulate, LDS reduce over 8 slots.
// ---------------------------------------------------------------------------
__global__ __launch_bounds__(128) void edge_agg(const unsigned short* __restrict__ xwb,
                                                const float* __restrict__ wgt,
                                                const int* __restrict__ rowptr,
                                                const int* __restrict__ ssorted,
                                                const float* __restrict__ bias,
                                                float* __restrict__ out,
                                                int final_layer) {
    int n = blockIdx.x;
    int t = threadIdx.x;
    int beg = rowptr[n], end = rowptr[n + 1];

    __shared__ float wbuf[32][HEADS];
    __shared__ int   sbuf[32];
    __shared__ float red[128][8];   // [thread][8 channels]

    int j = t >> 4;        // edge slot 0..7
    int q = t & 15;        // channel octet (channels 8q..8q+7)
    int qh = q >> 2;       // head of this octet
    float acc[8] = {0.f, 0.f, 0.f, 0.f, 0.f, 0.f, 0.f, 0.f};

    for (int cb = beg; cb < end; cb += 32) {
        int c = end - cb; if (c > 32) c = 32;
        if (t < c) sbuf[t] = ssorted[cb + t];
        {
            int l = t >> 2, hh = t & 3;
            if (l < c) wbuf[l][hh] = wgt[(cb + l) * HEADS + hh];
        }
        __syncthreads();
        for (int i = j; i < c; i += 8) {
            int s = sbuf[i];
            float w = wbuf[i][qh];
            u16x8 v = *(const u16x8*)(xwb + (size_t)s * FEAT + q * 8);
#pragma unroll
            for (int k = 0; k < 8; k++) acc[k] += w * bf2f(v[k]);
        }
        __syncthreads();
    }

#pragma unroll
    for (int k = 0; k < 8; k++) red[t][k] = acc[k];
    __syncthreads();

    if (!final_layer) {
        if (t < 16) {
            float tot[8];
#pragma unroll
            for (int k = 0; k < 8; k++) {
                float s = 0.f;
#pragma unroll
                for (int jj = 0; jj < 8; jj++) s += red[jj * 16 + t][k];
                s += bias[t * 8 + k];
                tot[k] = s > 0.f ? s : expm1f(s);   // ELU
            }
            float4* op = (float4*)(out + (size_t)n * FEAT + t * 8);
            op[0] = make_float4(tot[0], tot[1], tot[2], tot[3]);
            op[1] = make_float4(tot[4], tot[5], tot[6], tot[7]);
        }
    } else {
        // slot-reduce into a flat 128-channel row in LDS, then head-mean
        float tot[8];
        if (t < 16) {
#pragma unroll
            for (int k = 0; k < 8; k++) {
                float s = 0.f;
#pragma unroll
                for (int jj = 0; jj < 8; jj++) s += red[jj * 16 + t][k];
                tot[k] = s;
            }
        }
        __syncthreads();
        if (t < 16) {
#pragma unroll
            for (int k = 0; k < 8; k++) red[0][t * 8 + k] = tot[k];   // flat 128
        }
        __syncthreads();
        if (t < 8) {
            const float* row = &red[0][0];
#pragma unroll
            for (int k = 0; k < 4; k++) {
                int c = t * 4 + k;
                float v = (row[c] + row[c + 32] + row[c + 64] + row[c + 96]) * 0.25f
                          + bias[c];
                out[(size_t)n * HID + c] = v;
            }
        }
    }
}

// ---------------------------------------------------------------------------
// Launch
// ---------------------------------------------------------------------------
extern "C" void kernel_launch(void* const* d_in, const int* in_sizes, int n_in,
                              void* d_out, int out_size, void* d_ws, size_t ws_size,
                              hipStream_t stream) {
    const float* x   = (const float*)d_in[0];
    const int* eidx  = (const int*)d_in[1];
    const float* W1  = (const float*)d_in[2];
    const float* as1 = (const float*)d_in[3];
    const float* ad1 = (const float*)d_in[4];
    const float* b1  = (const float*)d_in[5];
    const float* W2  = (const float*)d_in[6];
    const float* as2 = (const float*)d_in[7];
    const float* ad2 = (const float*)d_in[8];
    const float* b2  = (const float*)d_in[9];
    const float* W3  = (const float*)d_in[10];
    const float* as3 = (const float*)d_in[11];
    const float* ad3 = (const float*)d_in[12];
    const float* b3  = (const float*)d_in[13];

    const int Nn = in_sizes[0] / FEAT;   // 100000
    const int E  = in_sizes[1] / 2;      // 1200000
    const int EP = E + Nn;

    char* w = (char*)d_ws;
    size_t off = 0;
    auto alloc = [&](size_t bytes) {
        void* p = w + off;
        off += (bytes + 255) & ~(size_t)255;
        return p;
    };
    float*          bufB   = (float*)alloc((size_t)Nn * FEAT * 4);   // inter-layer fp32
    unsigned short* xwb    = (unsigned short*)alloc((size_t)Nn * FEAT * 2);  // bf16 msgs
    float*          ssrc   = (float*)alloc((size_t)Nn * HEADS * 4);
    float*          sdst   = (float*)alloc((size_t)Nn * HEADS * 4);
    float*          scbuf  = (float*)alloc((size_t)EP * HEADS * 4);
    int*            rowptr = (int*)alloc((size_t)(Nn + 1) * 4);
    int*            cursor = (int*)alloc((size_t)Nn * 4);
    int*            deg    = (int*)alloc((size_t)Nn * 4);
    int*            ssort  = (int*)alloc((size_t)EP * 4);
    int*            dsort  = (int*)alloc((size_t)EP * 4);
    int*            bsum   = (int*)alloc(64 * 4);
    unsigned short* wth    = (unsigned short*)alloc((size_t)FEAT * FEAT * 2);
    unsigned short* wtl    = (unsigned short*)alloc((size_t)FEAT * FEAT * 2);
    (void)ws_size;

    // ---- CSR build (once; shared by all 3 layers)
    hipMemsetAsync(deg, 0, (size_t)Nn * 4, stream);
    hist_kernel<<<(E + 255) / 256, 256, 0, stream>>>(eidx, deg, E);
    int nscan = (Nn + SCAN_TILE - 1) / SCAN_TILE;
    scan_partial<<<nscan, SCAN_BLK, 0, stream>>>(deg, bsum, Nn);
    scan_bsum<<<1, 64, 0, stream>>>(bsum, nscan);
    scan_final<<<nscan, SCAN_BLK, 0, stream>>>(deg, bsum, rowptr, cursor, Nn);
    scatter_kernel<<<(EP + 255) / 256, 256, 0, stream>>>(eidx, cursor, ssort, dsort, E, Nn);

    const int gemm_grid = (Nn + 63) / 64;
    const int eg  = (EP + 255) / 256;
    const int sg  = (Nn * HEADS + 255) / 256;
    const int wpg = (FEAT * FEAT + 255) / 256;

    const float* Ws[3] = {W1, W2, W3};
    const float* as[3] = {as1, as2, as3};
    const float* ad[3] = {ad1, ad2, ad3};
    const float* bs[3] = {b1, b2, b3};

    const float* cur_in = x;
    for (int L = 0; L < 3; L++) {
        float* nxt = (L == 2) ? (float*)d_out : bufB;
        prep_w<<<wpg, 256, 0, stream>>>(Ws[L], wth, wtl);
        gemm_mfma<<<gemm_grid, 256, 0, stream>>>(cur_in, wth, wtl, as[L], ad[L],
                                                 xwb, ssrc, sdst, Nn);
        edge_scores<<<eg, 256, 0, stream>>>((const float4*)ssrc, (const float4*)sdst,
                                            ssort, dsort, (float4*)scbuf, EP);
        stats_weights<<<sg, 256, 0, stream>>>(scbuf, rowptr, Nn);
        edge_agg<<<Nn, 128, 0, stream>>>(xwb, scbuf, rowptr, ssort, bs[L], nxt, L == 2);
        cur_in = bufB;   // gemm of next layer reads bufB before edge_agg rewrites it
    }
}